// Round 4
// baseline (343.690 us; speedup 1.0000x reference)
//
#include <hip/hip_runtime.h>
#include <hip/hip_bf16.h>

typedef __attribute__((ext_vector_type(8))) short short8;
typedef __attribute__((ext_vector_type(4))) float f32x4;

__device__ inline float b2f(unsigned short u) {
    union { unsigned int i; float f; } c; c.i = ((unsigned int)u) << 16; return c.f;
}
__device__ inline unsigned short f2b(float f) {
    __hip_bfloat16 h = __float2bfloat16(f);
    return *reinterpret_cast<unsigned short*>(&h);
}

// async global->LDS, 16 B per lane; LDS dest = wave-uniform base + lane*16
__device__ inline void gl_lds16(const unsigned short* g, unsigned short* ldsbase) {
    __builtin_amdgcn_global_load_lds(
        (const __attribute__((address_space(1))) unsigned int*)(g),
        (__attribute__((address_space(3))) unsigned int*)(ldsbase),
        16, 0, 0);
}

// ---- merged prep: weights transpose/convert + x convert + bvo, ONE dispatch ----
// grid (32,32,7): z 0-2 transpose {Wq,Wk,Wo}->bf16^T; z=3 convert Wv; z=4,5 convert x;
// z=6 (y==0 only): bvo[n] = sum_k bv[k]*Wo[k][n] + bo[n] from fp32 Wo.
__global__ __launch_bounds__(256) void prep(
    const float* __restrict__ x,
    const float* __restrict__ Wq, const float* __restrict__ Wk,
    const float* __restrict__ Wo, const float* __restrict__ Wv,
    const float* __restrict__ bv, const float* __restrict__ bo,
    unsigned short* __restrict__ xb,
    unsigned short* __restrict__ Wqt, unsigned short* __restrict__ Wkt,
    unsigned short* __restrict__ Wot, unsigned short* __restrict__ Wvb,
    float* __restrict__ bvo)
{
    const int z = blockIdx.z;
    const int t = threadIdx.x;
    __shared__ float tile[32][33];

    if (z < 3) {
        const float* src = z == 0 ? Wq : z == 1 ? Wk : Wo;
        unsigned short* dst = z == 0 ? Wqt : z == 1 ? Wkt : Wot;
        const int c0 = blockIdx.x * 32, r0 = blockIdx.y * 32;
        const int tx = t & 31, ty = t >> 5;
        #pragma unroll
        for (int i = ty; i < 32; i += 8)
            tile[i][tx] = src[(long)(r0 + i) * 1024 + c0 + tx];
        __syncthreads();
        #pragma unroll
        for (int i = ty; i < 32; i += 8)
            dst[(long)(c0 + i) * 1024 + r0 + tx] = f2b(tile[tx][i]);
        return;
    }
    if (z == 3) {
        const int i = (blockIdx.y * 32 + blockIdx.x) * 256 + t;
        float4 v = ((const float4*)Wv)[i];
        union { unsigned short u[4]; unsigned long long ll; } p;
        p.u[0] = f2b(v.x); p.u[1] = f2b(v.y); p.u[2] = f2b(v.z); p.u[3] = f2b(v.w);
        ((unsigned long long*)Wvb)[i] = p.ll;
        return;
    }
    if (z < 6) {
        const int bl = (z - 4) * 1024 + blockIdx.y * 32 + blockIdx.x;
        #pragma unroll
        for (int k = 0; k < 4; k++) {
            const int i = bl * 1024 + k * 256 + t;
            float4 v = ((const float4*)x)[i];
            union { unsigned short u[4]; unsigned long long ll; } p;
            p.u[0] = f2b(v.x); p.u[1] = f2b(v.y); p.u[2] = f2b(v.z); p.u[3] = f2b(v.w);
            ((unsigned long long*)xb)[i] = p.ll;
        }
        return;
    }
    // z == 6: bvo. Only y==0 blocks work; block x handles n in [x*32, x*32+32).
    if (blockIdx.y != 0) return;
    const int tx = t & 31, ty = t >> 5;
    const int n = blockIdx.x * 32 + tx;
    float acc = 0.f;
    #pragma unroll 4
    for (int j = 0; j < 128; j++) {
        const int k = ty * 128 + j;
        acc += Wo[(long)k * 1024 + n] * bv[k];
    }
    float* red = &tile[0][0];  // reuse: 8x32 floats
    red[ty * 32 + tx] = acc;
    __syncthreads();
    if (ty == 0) {
        float s = 0.f;
        #pragma unroll
        for (int j = 0; j < 8; j++) s += red[j * 32 + tx];
        bvo[n] = s + bo[n];
    }
}

// ---- 128-tile K-loop body (shared by gemm128 and qkv_proj) ----
#define TILE_KLOOP(As, Bs, gA, lda, gB, ldb, Keff) \
    for (int k0 = 0; k0 < (Keff); k0 += 64) { \
        _Pragma("unroll") for (int p = 0; p < 2; p++) \
            _Pragma("unroll") for (int h = 0; h < 2; h++) { \
                gl_lds16((gA) + (long)h * 16 * (lda) + k0 + p * 32, \
                         &(As)[p * 4096 + (w * 32 + h * 16) * 32]); \
                gl_lds16((gB) + (long)h * 16 * (ldb) + k0 + p * 32, \
                         &(Bs)[p * 4096 + (w * 32 + h * 16) * 32]); \
            } \
        __syncthreads(); \
        _Pragma("unroll") for (int p = 0; p < 2; p++) { \
            short8 af[4], bfr[4]; \
            _Pragma("unroll") for (int mi = 0; mi < 4; mi++) \
                af[mi] = *(const short8*)&(As)[p * 4096 + (wr * 64 + mi * 16 + lrow) * 32 + quad * 8]; \
            _Pragma("unroll") for (int ni = 0; ni < 4; ni++) \
                bfr[ni] = *(const short8*)&(Bs)[p * 4096 + (wc * 64 + ni * 16 + lrow) * 32 + quad * 8]; \
            _Pragma("unroll") for (int mi = 0; mi < 4; mi++) \
                _Pragma("unroll") for (int ni = 0; ni < 4; ni++) \
                    acc[mi][ni] = __builtin_amdgcn_mfma_f32_16x16x32_bf16( \
                        af[mi], bfr[ni], acc[mi][ni], 0, 0, 0); \
        } \
        __syncthreads(); \
    }

#define TILE_DECLS \
    const int t = threadIdx.x, lane = t & 63, w = t >> 6; \
    const int wr = w >> 1, wc = w & 1; \
    const int lrow = lane & 15, quad = lane >> 4; \
    f32x4 acc[4][4]; \
    _Pragma("unroll") for (int i = 0; i < 4; i++) \
        _Pragma("unroll") for (int j = 0; j < 4; j++) \
            acc[i][j] = (f32x4){0.f, 0.f, 0.f, 0.f};

template<bool TRI, bool KCAUSAL, int OMODE>
__global__ __launch_bounds__(256) void gemm128(
    const unsigned short* __restrict__ A, const unsigned short* __restrict__ Bt,
    const float* __restrict__ bias, void* __restrict__ Cv,
    int K, int lda, int ldb, int ldc, long sA, long sB, long sC, float scale)
{
    __shared__ __attribute__((aligned(16))) unsigned short As[2 * 128 * 32];
    __shared__ __attribute__((aligned(16))) unsigned short Bs[2 * 128 * 32];
    int bm, bn, bz;
    if (TRI) {
        // heavy-first: reverse the triangular index so large-K tiles launch first
        const int q = gridDim.x - 1 - blockIdx.x;
        bm = (int)((sqrtf(8.f * q + 1.f) - 1.f) * 0.5f);
        while ((bm + 1) * (bm + 2) / 2 <= q) bm++;
        while (bm * (bm + 1) / 2 > q) bm--;
        bn = q - bm * (bm + 1) / 2;
        bz = blockIdx.y;
    } else {
        bm = KCAUSAL ? (gridDim.x - 1 - blockIdx.x) : blockIdx.x;
        bn = blockIdx.y; bz = blockIdx.z;
    }
    A  += (long)bz * sA;
    Bt += (long)bz * sB;
    const int m0 = bm * 128, n0 = bn * 128;

    TILE_DECLS

    const int Keff = KCAUSAL ? ((bm + 1) * 128 < K ? (bm + 1) * 128 : K) : K;
    const unsigned short* gA = A  + (long)(m0 + w * 32 + (lane >> 2)) * lda + (lane & 3) * 8;
    const unsigned short* gB = Bt + (long)(n0 + w * 32 + (lane >> 2)) * ldb + (lane & 3) * 8;
    TILE_KLOOP(As, Bs, gA, lda, gB, ldb, Keff)

    #pragma unroll
    for (int mi = 0; mi < 4; mi++) {
        const int m = m0 + wr * 64 + mi * 16 + quad * 4;
        #pragma unroll
        for (int ni = 0; ni < 4; ni++) {
            const int n = n0 + wc * 64 + ni * 16 + lrow;
            const float bvl = bias ? bias[n] : 0.f;
            #pragma unroll
            for (int rg = 0; rg < 4; rg++) {
                const float val = acc[mi][ni][rg] * scale + bvl;
                if (OMODE == 1)
                    ((float*)Cv)[(long)bz * sC + (long)(m + rg) * ldc + n] = val;
                else
                    ((unsigned short*)Cv)[(long)bz * sC + (long)(m + rg) * ldc + n] = f2b(val);
            }
        }
    }
}

// Fused QKV projection, 128-tile structure, LDS-transposed coalesced epilogues.
// grid (24,64): x = (r<<3)|bnn (fast), y = bm -> 24 consecutive blocks share one
// x A-panel (L2-hot), cutting x HBM re-fetch ~3x -> ~1x.
__global__ __launch_bounds__(256) void qkv_proj(
    const unsigned short* __restrict__ A,
    const unsigned short* __restrict__ Wqt, const unsigned short* __restrict__ Wkt,
    const unsigned short* __restrict__ Wvot,
    const float* __restrict__ bq, const float* __restrict__ bk,
    unsigned short* __restrict__ Q, unsigned short* __restrict__ Km,
    unsigned short* __restrict__ Vot)
{
    __shared__ __attribute__((aligned(16))) unsigned short pool[16384];  // 32 KiB
    unsigned short* As = pool;
    unsigned short* Bs = pool + 8192;

    const int bm = blockIdx.y, bx = blockIdx.x;
    const int r = bx >> 3, bnn = bx & 7;
    const unsigned short* Bt = (r == 0) ? Wqt : (r == 1) ? Wkt : Wvot;
    const float* bias = (r == 0) ? bq : (r == 1) ? bk : nullptr;
    const int m0 = bm * 128, n0 = bnn * 128;

    TILE_DECLS

    const unsigned short* gA = A  + (long)(m0 + w * 32 + (lane >> 2)) * 1024 + (lane & 3) * 8;
    const unsigned short* gB = Bt + (long)(n0 + w * 32 + (lane >> 2)) * 1024 + (lane & 3) * 8;
    TILE_KLOOP(As, Bs, gA, 1024, gB, 1024, 1024)
    // loop's final __syncthreads: all LDS reads done -> pool reusable

    if (r < 2) {
        // pool[m][n] linear, then coalesced 256-B row stores
        #pragma unroll
        for (int mi = 0; mi < 4; mi++) {
            #pragma unroll
            for (int ni = 0; ni < 4; ni++) {
                const int n_l = wc * 64 + ni * 16 + lrow;
                const float bvl = bias[n0 + n_l];
                #pragma unroll
                for (int rg = 0; rg < 4; rg++) {
                    const int m_l = wr * 64 + mi * 16 + quad * 4 + rg;
                    pool[m_l * 128 + n_l] = f2b(acc[mi][ni][rg] + bvl);
                }
            }
        }
        __syncthreads();
        unsigned short* out = (r == 0) ? Q : Km;
        #pragma unroll
        for (int it = 0; it < 8; it++) {
            const int idx = it * 256 + t;
            const int m_l = idx >> 4, c = idx & 15;
            short8 v = *(const short8*)&pool[m_l * 128 + c * 8];
            *(short8*)&out[(long)(m0 + m_l) * 1024 + n0 + c * 8] = v;
        }
    } else {
        // transposed: pool[n][m ^ ((n&15)<<3)] (XOR keeps rg-quads contiguous and
        // spreads the 256-B row stride across banks), then coalesced Vot rows.
        #pragma unroll
        for (int mi = 0; mi < 4; mi++) {
            #pragma unroll
            for (int ni = 0; ni < 4; ni++) {
                const int n_l = wc * 64 + ni * 16 + lrow;
                const int mb = wr * 64 + mi * 16 + quad * 4;
                union { unsigned short u[4]; unsigned long long ll; } pk;
                #pragma unroll
                for (int rg = 0; rg < 4; rg++) pk.u[rg] = f2b(acc[mi][ni][rg]);
                *(unsigned long long*)&pool[n_l * 128 + (mb ^ ((n_l & 15) << 3))] = pk.ll;
            }
        }
        __syncthreads();
        #pragma unroll
        for (int it = 0; it < 8; it++) {
            const int idx = it * 256 + t;
            const int n_l = idx >> 4, c = idx & 15;
            short8 v = *(const short8*)&pool[n_l * 128 + ((c * 8) ^ ((n_l & 15) << 3))];
            *(short8*)&Vot[(long)(n0 + n_l) * 8192 + m0 + c * 8] = v;
        }
    }
}

// Single-pass causal row softmax, 128-granular padding (PV uses 128-tile K cap).
// grid 2048: block i handles row i of all 4 batches (identical causal length ->
// perfect balance), amortizing block launch 4x.
__global__ __launch_bounds__(256) void softmax_causal(unsigned short* __restrict__ S)
{
    const int i = blockIdx.x;
    const int t = threadIdx.x;
    const int padded = ((i >> 7) + 1) << 7;
    const int j0 = t * 8;
    const bool active = j0 < padded;

    __shared__ float red[4];

    for (int b = 0; b < 4; b++) {
        unsigned short* base = S + ((long)b * 2048 + i) * 2048;

        float v[8];
        if (active) {
            short8 s8 = *(const short8*)(base + j0);
            #pragma unroll
            for (int jj = 0; jj < 8; jj++)
                v[jj] = (j0 + jj <= i) ? b2f((unsigned short)s8[jj]) : -3.0e38f;
        } else {
            #pragma unroll
            for (int jj = 0; jj < 8; jj++) v[jj] = -3.0e38f;
        }

        float lmax = v[0];
        #pragma unroll
        for (int jj = 1; jj < 8; jj++) lmax = fmaxf(lmax, v[jj]);
        #pragma unroll
        for (int off = 32; off > 0; off >>= 1) lmax = fmaxf(lmax, __shfl_xor(lmax, off, 64));
        if ((t & 63) == 0) red[t >> 6] = lmax;
        __syncthreads();
        const float gmax = fmaxf(fmaxf(red[0], red[1]), fmaxf(red[2], red[3]));
        __syncthreads();

        float lsum = 0.f;
        #pragma unroll
        for (int jj = 0; jj < 8; jj++) {
            v[jj] = (v[jj] > -1.0e37f) ? __expf(v[jj] - gmax) : 0.f;
            lsum += v[jj];
        }
        #pragma unroll
        for (int off = 32; off > 0; off >>= 1) lsum += __shfl_xor(lsum, off, 64);
        if ((t & 63) == 0) red[t >> 6] = lsum;
        __syncthreads();
        const float inv = 1.0f / (red[0] + red[1] + red[2] + red[3]);

        if (active) {
            short8 p8;
            #pragma unroll
            for (int jj = 0; jj < 8; jj++) p8[jj] = (short)f2b(v[jj] * inv);
            *(short8*)(base + j0) = p8;
        }
        __syncthreads();  // red[] reused next batch
    }
}

extern "C" void kernel_launch(void* const* d_in, const int* in_sizes, int n_in,
                              void* d_out, int out_size, void* d_ws, size_t ws_size,
                              hipStream_t stream)
{
    const float* x  = (const float*)d_in[0];
    const float* Wq = (const float*)d_in[2];
    const float* bq = (const float*)d_in[3];
    const float* Wk = (const float*)d_in[4];
    const float* bk = (const float*)d_in[5];
    const float* Wv = (const float*)d_in[6];
    const float* bv = (const float*)d_in[7];
    const float* Wo = (const float*)d_in[8];
    const float* bo = (const float*)d_in[9];

    unsigned short* ws = (unsigned short*)d_ws;
    const long XSZ = 8192L * 1024;
    const long WSZ = 1024L * 1024;
    unsigned short* xb   = ws;                // [8192,1024] bf16
    unsigned short* Wqt  = ws + XSZ;          // Wq^T bf16
    unsigned short* Wkt  = Wqt + WSZ;         // Wk^T bf16
    unsigned short* Wot  = Wkt + WSZ;         // Wo^T bf16
    unsigned short* Wvb  = Wot + WSZ;         // Wv bf16 (plain)
    unsigned short* Wvot = Wvb + WSZ;         // (Wv@Wo)^T bf16
    unsigned short* Q    = Wvot + WSZ;        // [8192,1024]
    unsigned short* Km   = Q + XSZ;           // [8192,1024]
    unsigned short* Vot  = Km + XSZ;          // [1024,8192] = (x@Wvo)^T
    unsigned short* S    = Vot + XSZ;         // [4][2048,2048] (S -> P in place)
    float*          bvo  = (float*)(S + 4L * 2048 * 2048);   // [1024] fp32

    const dim3 blk(256);

    // merged prep: weights + x convert + bvo, one dispatch
    prep<<<dim3(32, 32, 7), blk, 0, stream>>>(
        x, Wq, Wk, Wo, Wv, bv, bo, xb, Wqt, Wkt, Wot, Wvb, bvo);

    // Wvo^T = Wo^T @ Wv^T
    gemm128<false, false, 0><<<dim3(8, 8, 1), blk, 0, stream>>>(
        Wot, Wvb, nullptr, Wvot, 1024, 1024, 1024, 1024, 0, 0, 0, 1.f);

    // fused QKV projection (128-tile, coalesced epilogues, x-reuse grid order)
    qkv_proj<<<dim3(24, 64), blk, 0, stream>>>(
        xb, Wqt, Wkt, Wvot, bq, bk, Q, Km, Vot);

    // S = Q K^T / sqrt(D), triangular grid, heavy-first
    gemm128<true, false, 0><<<dim3(136, 4), blk, 0, stream>>>(
        Q, Km, nullptr, S, 1024, 1024, 1024, 2048,
        2048L * 1024, 2048L * 1024, 2048L * 2048, 0.03125f);

    softmax_causal<<<dim3(2048), blk, 0, stream>>>(S);

    // out = P @ Vo + bvo  (fp32, final output), causal K cap, heavy tiles first
    gemm128<false, true, 1><<<dim3(16, 8, 4), blk, 0, stream>>>(
        S, Vot, bvo, (float*)d_out, 2048, 2048, 8192, 1024,
        2048L * 2048, 2048, 2048L * 1024, 1.f);
}

// Round 5
// 341.716 us; speedup vs baseline: 1.0058x; 1.0058x over previous
//
#include <hip/hip_runtime.h>
#include <hip/hip_bf16.h>

typedef __attribute__((ext_vector_type(8))) short short8;
typedef __attribute__((ext_vector_type(4))) float f32x4;

__device__ inline float b2f(unsigned short u) {
    union { unsigned int i; float f; } c; c.i = ((unsigned int)u) << 16; return c.f;
}
__device__ inline unsigned short f2b(float f) {
    __hip_bfloat16 h = __float2bfloat16(f);
    return *reinterpret_cast<unsigned short*>(&h);
}

// async global->LDS, 16 B per lane; LDS dest = wave-uniform base + lane*16
__device__ inline void gl_lds16(const unsigned short* g, unsigned short* ldsbase) {
    __builtin_amdgcn_global_load_lds(
        (const __attribute__((address_space(1))) unsigned int*)(g),
        (__attribute__((address_space(3))) unsigned int*)(ldsbase),
        16, 0, 0);
}

// ---- merged prep: weights transpose/convert + x convert + bvo, ONE dispatch ----
// grid (32,32,7): z 0-2 transpose {Wq,Wk,Wo}->bf16^T; z=3 convert Wv; z=4,5 convert x;
// z=6 (y==0 only): bvo[n] = sum_k bv[k]*Wo[k][n] + bo[n] from fp32 Wo.
__global__ __launch_bounds__(256) void prep(
    const float* __restrict__ x,
    const float* __restrict__ Wq, const float* __restrict__ Wk,
    const float* __restrict__ Wo, const float* __restrict__ Wv,
    const float* __restrict__ bv, const float* __restrict__ bo,
    unsigned short* __restrict__ xb,
    unsigned short* __restrict__ Wqt, unsigned short* __restrict__ Wkt,
    unsigned short* __restrict__ Wot, unsigned short* __restrict__ Wvb,
    float* __restrict__ bvo)
{
    const int z = blockIdx.z;
    const int t = threadIdx.x;
    __shared__ float tile[32][33];

    if (z < 3) {
        const float* src = z == 0 ? Wq : z == 1 ? Wk : Wo;
        unsigned short* dst = z == 0 ? Wqt : z == 1 ? Wkt : Wot;
        const int c0 = blockIdx.x * 32, r0 = blockIdx.y * 32;
        const int tx = t & 31, ty = t >> 5;
        #pragma unroll
        for (int i = ty; i < 32; i += 8)
            tile[i][tx] = src[(long)(r0 + i) * 1024 + c0 + tx];
        __syncthreads();
        #pragma unroll
        for (int i = ty; i < 32; i += 8)
            dst[(long)(c0 + i) * 1024 + r0 + tx] = f2b(tile[tx][i]);
        return;
    }
    if (z == 3) {
        const int i = (blockIdx.y * 32 + blockIdx.x) * 256 + t;
        float4 v = ((const float4*)Wv)[i];
        union { unsigned short u[4]; unsigned long long ll; } p;
        p.u[0] = f2b(v.x); p.u[1] = f2b(v.y); p.u[2] = f2b(v.z); p.u[3] = f2b(v.w);
        ((unsigned long long*)Wvb)[i] = p.ll;
        return;
    }
    if (z < 6) {
        const int bl = (z - 4) * 1024 + blockIdx.y * 32 + blockIdx.x;
        #pragma unroll
        for (int k = 0; k < 4; k++) {
            const int i = bl * 1024 + k * 256 + t;
            float4 v = ((const float4*)x)[i];
            union { unsigned short u[4]; unsigned long long ll; } p;
            p.u[0] = f2b(v.x); p.u[1] = f2b(v.y); p.u[2] = f2b(v.z); p.u[3] = f2b(v.w);
            ((unsigned long long*)xb)[i] = p.ll;
        }
        return;
    }
    // z == 6: bvo. Only y==0 blocks work; block x handles n in [x*32, x*32+32).
    if (blockIdx.y != 0) return;
    const int tx = t & 31, ty = t >> 5;
    const int n = blockIdx.x * 32 + tx;
    float acc = 0.f;
    #pragma unroll 4
    for (int j = 0; j < 128; j++) {
        const int k = ty * 128 + j;
        acc += Wo[(long)k * 1024 + n] * bv[k];
    }
    float* red = &tile[0][0];  // reuse: 8x32 floats
    red[ty * 32 + tx] = acc;
    __syncthreads();
    if (ty == 0) {
        float s = 0.f;
        #pragma unroll
        for (int j = 0; j < 8; j++) s += red[j * 32 + tx];
        bvo[n] = s + bo[n];
    }
}

// ---- 128-tile K-loop body (shared by gemm128 and qkv_proj) ----
#define TILE_KLOOP(As, Bs, gA, lda, gB, ldb, Keff) \
    for (int k0 = 0; k0 < (Keff); k0 += 64) { \
        _Pragma("unroll") for (int p = 0; p < 2; p++) \
            _Pragma("unroll") for (int h = 0; h < 2; h++) { \
                gl_lds16((gA) + (long)h * 16 * (lda) + k0 + p * 32, \
                         &(As)[p * 4096 + (w * 32 + h * 16) * 32]); \
                gl_lds16((gB) + (long)h * 16 * (ldb) + k0 + p * 32, \
                         &(Bs)[p * 4096 + (w * 32 + h * 16) * 32]); \
            } \
        __syncthreads(); \
        _Pragma("unroll") for (int p = 0; p < 2; p++) { \
            short8 af[4], bfr[4]; \
            _Pragma("unroll") for (int mi = 0; mi < 4; mi++) \
                af[mi] = *(const short8*)&(As)[p * 4096 + (wr * 64 + mi * 16 + lrow) * 32 + quad * 8]; \
            _Pragma("unroll") for (int ni = 0; ni < 4; ni++) \
                bfr[ni] = *(const short8*)&(Bs)[p * 4096 + (wc * 64 + ni * 16 + lrow) * 32 + quad * 8]; \
            _Pragma("unroll") for (int mi = 0; mi < 4; mi++) \
                _Pragma("unroll") for (int ni = 0; ni < 4; ni++) \
                    acc[mi][ni] = __builtin_amdgcn_mfma_f32_16x16x32_bf16( \
                        af[mi], bfr[ni], acc[mi][ni], 0, 0, 0); \
        } \
        __syncthreads(); \
    }

#define TILE_DECLS \
    const int t = threadIdx.x, lane = t & 63, w = t >> 6; \
    const int wr = w >> 1, wc = w & 1; \
    const int lrow = lane & 15, quad = lane >> 4; \
    f32x4 acc[4][4]; \
    _Pragma("unroll") for (int i = 0; i < 4; i++) \
        _Pragma("unroll") for (int j = 0; j < 4; j++) \
            acc[i][j] = (f32x4){0.f, 0.f, 0.f, 0.f};

template<bool TRI, bool KCAUSAL, int OMODE>
__global__ __launch_bounds__(256) void gemm128(
    const unsigned short* __restrict__ A, const unsigned short* __restrict__ Bt,
    const float* __restrict__ bias, void* __restrict__ Cv,
    int K, int lda, int ldb, int ldc, long sA, long sB, long sC, float scale)
{
    __shared__ __attribute__((aligned(16))) unsigned short As[2 * 128 * 32];
    __shared__ __attribute__((aligned(16))) unsigned short Bs[2 * 128 * 32];
    int bm, bn, bz;
    if (TRI) {
        // heavy-first: reverse the triangular index so large-K tiles launch first
        const int q = gridDim.x - 1 - blockIdx.x;
        bm = (int)((sqrtf(8.f * q + 1.f) - 1.f) * 0.5f);
        while ((bm + 1) * (bm + 2) / 2 <= q) bm++;
        while (bm * (bm + 1) / 2 > q) bm--;
        bn = q - bm * (bm + 1) / 2;
        bz = blockIdx.y;
    } else {
        bm = KCAUSAL ? (gridDim.x - 1 - blockIdx.x) : blockIdx.x;
        bn = blockIdx.y; bz = blockIdx.z;
    }
    A  += (long)bz * sA;
    Bt += (long)bz * sB;
    const int m0 = bm * 128, n0 = bn * 128;

    TILE_DECLS

    const int Keff = KCAUSAL ? ((bm + 1) * 128 < K ? (bm + 1) * 128 : K) : K;
    const unsigned short* gA = A  + (long)(m0 + w * 32 + (lane >> 2)) * lda + (lane & 3) * 8;
    const unsigned short* gB = Bt + (long)(n0 + w * 32 + (lane >> 2)) * ldb + (lane & 3) * 8;
    TILE_KLOOP(As, Bs, gA, lda, gB, ldb, Keff)

    #pragma unroll
    for (int mi = 0; mi < 4; mi++) {
        const int m = m0 + wr * 64 + mi * 16 + quad * 4;
        #pragma unroll
        for (int ni = 0; ni < 4; ni++) {
            const int n = n0 + wc * 64 + ni * 16 + lrow;
            const float bvl = bias ? bias[n] : 0.f;
            #pragma unroll
            for (int rg = 0; rg < 4; rg++) {
                const float val = acc[mi][ni][rg] * scale + bvl;
                if (OMODE == 1)
                    ((float*)Cv)[(long)bz * sC + (long)(m + rg) * ldc + n] = val;
                else
                    ((unsigned short*)Cv)[(long)bz * sC + (long)(m + rg) * ldc + n] = f2b(val);
            }
        }
    }
}

// Fused QKV projection, 128-tile structure, LDS-transposed coalesced epilogues.
// 1D grid 1536, XCD-partitioned: xcd = bid&7 gets bm in [xcd*8, xcd*8+8)
// (2 MB of x, L2-resident) and sweeps all 24 (r,bnn) weight panels bm-fastest
// (concurrent blocks share one weight panel). x should HBM-fetch ~once.
__global__ __launch_bounds__(256) void qkv_proj(
    const unsigned short* __restrict__ A,
    const unsigned short* __restrict__ Wqt, const unsigned short* __restrict__ Wkt,
    const unsigned short* __restrict__ Wvot,
    const float* __restrict__ bq, const float* __restrict__ bk,
    unsigned short* __restrict__ Q, unsigned short* __restrict__ Km,
    unsigned short* __restrict__ Vot)
{
    __shared__ __attribute__((aligned(16))) unsigned short pool[16384];  // 32 KiB
    unsigned short* As = pool;
    unsigned short* Bs = pool + 8192;

    const int bid = blockIdx.x;
    const int xcd = bid & 7, slot = bid >> 3;   // 192 slots per XCD
    const int bm  = xcd * 8 + (slot & 7);       // 8 contiguous bm per XCD
    const int pan = slot >> 3;                  // 0..23, bm-fastest within pan
    const int r = pan >> 3, bnn = pan & 7;
    const unsigned short* Bt = (r == 0) ? Wqt : (r == 1) ? Wkt : Wvot;
    const float* bias = (r == 0) ? bq : (r == 1) ? bk : nullptr;
    const int m0 = bm * 128, n0 = bnn * 128;

    TILE_DECLS

    const unsigned short* gA = A  + (long)(m0 + w * 32 + (lane >> 2)) * 1024 + (lane & 3) * 8;
    const unsigned short* gB = Bt + (long)(n0 + w * 32 + (lane >> 2)) * 1024 + (lane & 3) * 8;
    TILE_KLOOP(As, Bs, gA, 1024, gB, 1024, 1024)
    // loop's final __syncthreads: all LDS reads done -> pool reusable

    if (r < 2) {
        // pool[m][n] linear, then coalesced 256-B row stores
        #pragma unroll
        for (int mi = 0; mi < 4; mi++) {
            #pragma unroll
            for (int ni = 0; ni < 4; ni++) {
                const int n_l = wc * 64 + ni * 16 + lrow;
                const float bvl = bias[n0 + n_l];
                #pragma unroll
                for (int rg = 0; rg < 4; rg++) {
                    const int m_l = wr * 64 + mi * 16 + quad * 4 + rg;
                    pool[m_l * 128 + n_l] = f2b(acc[mi][ni][rg] + bvl);
                }
            }
        }
        __syncthreads();
        unsigned short* out = (r == 0) ? Q : Km;
        #pragma unroll
        for (int it = 0; it < 8; it++) {
            const int idx = it * 256 + t;
            const int m_l = idx >> 4, c = idx & 15;
            short8 v = *(const short8*)&pool[m_l * 128 + c * 8];
            *(short8*)&out[(long)(m0 + m_l) * 1024 + n0 + c * 8] = v;
        }
    } else {
        // transposed: pool[n][m ^ ((n&15)<<3)] (XOR keeps rg-quads contiguous and
        // spreads the 256-B row stride across banks), then coalesced Vot rows.
        #pragma unroll
        for (int mi = 0; mi < 4; mi++) {
            #pragma unroll
            for (int ni = 0; ni < 4; ni++) {
                const int n_l = wc * 64 + ni * 16 + lrow;
                const int mb = wr * 64 + mi * 16 + quad * 4;
                union { unsigned short u[4]; unsigned long long ll; } pk;
                #pragma unroll
                for (int rg = 0; rg < 4; rg++) pk.u[rg] = f2b(acc[mi][ni][rg]);
                *(unsigned long long*)&pool[n_l * 128 + (mb ^ ((n_l & 15) << 3))] = pk.ll;
            }
        }
        __syncthreads();
        #pragma unroll
        for (int it = 0; it < 8; it++) {
            const int idx = it * 256 + t;
            const int n_l = idx >> 4, c = idx & 15;
            short8 v = *(const short8*)&pool[n_l * 128 + ((c * 8) ^ ((n_l & 15) << 3))];
            *(short8*)&Vot[(long)(n0 + n_l) * 8192 + m0 + c * 8] = v;
        }
    }
}

// Single-pass causal row softmax, 128-granular padding (PV uses 128-tile K cap).
// grid 2048: block i handles row i of all 4 batches (identical causal length ->
// perfect balance), amortizing block launch 4x.
__global__ __launch_bounds__(256) void softmax_causal(unsigned short* __restrict__ S)
{
    const int i = blockIdx.x;
    const int t = threadIdx.x;
    const int padded = ((i >> 7) + 1) << 7;
    const int j0 = t * 8;
    const bool active = j0 < padded;

    __shared__ float red[4];

    for (int b = 0; b < 4; b++) {
        unsigned short* base = S + ((long)b * 2048 + i) * 2048;

        float v[8];
        if (active) {
            short8 s8 = *(const short8*)(base + j0);
            #pragma unroll
            for (int jj = 0; jj < 8; jj++)
                v[jj] = (j0 + jj <= i) ? b2f((unsigned short)s8[jj]) : -3.0e38f;
        } else {
            #pragma unroll
            for (int jj = 0; jj < 8; jj++) v[jj] = -3.0e38f;
        }

        float lmax = v[0];
        #pragma unroll
        for (int jj = 1; jj < 8; jj++) lmax = fmaxf(lmax, v[jj]);
        #pragma unroll
        for (int off = 32; off > 0; off >>= 1) lmax = fmaxf(lmax, __shfl_xor(lmax, off, 64));
        if ((t & 63) == 0) red[t >> 6] = lmax;
        __syncthreads();
        const float gmax = fmaxf(fmaxf(red[0], red[1]), fmaxf(red[2], red[3]));
        __syncthreads();

        float lsum = 0.f;
        #pragma unroll
        for (int jj = 0; jj < 8; jj++) {
            v[jj] = (v[jj] > -1.0e37f) ? __expf(v[jj] - gmax) : 0.f;
            lsum += v[jj];
        }
        #pragma unroll
        for (int off = 32; off > 0; off >>= 1) lsum += __shfl_xor(lsum, off, 64);
        if ((t & 63) == 0) red[t >> 6] = lsum;
        __syncthreads();
        const float inv = 1.0f / (red[0] + red[1] + red[2] + red[3]);

        if (active) {
            short8 p8;
            #pragma unroll
            for (int jj = 0; jj < 8; jj++) p8[jj] = (short)f2b(v[jj] * inv);
            *(short8*)(base + j0) = p8;
        }
        __syncthreads();  // red[] reused next batch
    }
}

extern "C" void kernel_launch(void* const* d_in, const int* in_sizes, int n_in,
                              void* d_out, int out_size, void* d_ws, size_t ws_size,
                              hipStream_t stream)
{
    const float* x  = (const float*)d_in[0];
    const float* Wq = (const float*)d_in[2];
    const float* bq = (const float*)d_in[3];
    const float* Wk = (const float*)d_in[4];
    const float* bk = (const float*)d_in[5];
    const float* Wv = (const float*)d_in[6];
    const float* bv = (const float*)d_in[7];
    const float* Wo = (const float*)d_in[8];
    const float* bo = (const float*)d_in[9];

    unsigned short* ws = (unsigned short*)d_ws;
    const long XSZ = 8192L * 1024;
    const long WSZ = 1024L * 1024;
    unsigned short* xb   = ws;                // [8192,1024] bf16
    unsigned short* Wqt  = ws + XSZ;          // Wq^T bf16
    unsigned short* Wkt  = Wqt + WSZ;         // Wk^T bf16
    unsigned short* Wot  = Wkt + WSZ;         // Wo^T bf16
    unsigned short* Wvb  = Wot + WSZ;         // Wv bf16 (plain)
    unsigned short* Wvot = Wvb + WSZ;         // (Wv@Wo)^T bf16
    unsigned short* Q    = Wvot + WSZ;        // [8192,1024]
    unsigned short* Km   = Q + XSZ;           // [8192,1024]
    unsigned short* Vot  = Km + XSZ;          // [1024,8192] = (x@Wvo)^T
    unsigned short* S    = Vot + XSZ;         // [4][2048,2048] (S -> P in place)
    float*          bvo  = (float*)(S + 4L * 2048 * 2048);   // [1024] fp32

    const dim3 blk(256);

    // merged prep: weights + x convert + bvo, one dispatch
    prep<<<dim3(32, 32, 7), blk, 0, stream>>>(
        x, Wq, Wk, Wo, Wv, bv, bo, xb, Wqt, Wkt, Wot, Wvb, bvo);

    // Wvo^T = Wo^T @ Wv^T
    gemm128<false, false, 0><<<dim3(8, 8, 1), blk, 0, stream>>>(
        Wot, Wvb, nullptr, Wvot, 1024, 1024, 1024, 1024, 0, 0, 0, 1.f);

    // fused QKV projection (128-tile, coalesced epilogues, XCD-partitioned grid)
    qkv_proj<<<dim3(1536), blk, 0, stream>>>(
        xb, Wqt, Wkt, Wvot, bq, bk, Q, Km, Vot);

    // S = Q K^T / sqrt(D), triangular grid, heavy-first
    gemm128<true, false, 0><<<dim3(136, 4), blk, 0, stream>>>(
        Q, Km, nullptr, S, 1024, 1024, 1024, 2048,
        2048L * 1024, 2048L * 1024, 2048L * 2048, 0.03125f);

    softmax_causal<<<dim3(2048), blk, 0, stream>>>(S);

    // out = P @ Vo + bvo  (fp32, final output), causal K cap, heavy tiles first
    gemm128<false, true, 1><<<dim3(16, 8, 4), blk, 0, stream>>>(
        S, Vot, bvo, (float*)d_out, 2048, 2048, 8192, 1024,
        2048L * 2048, 2048, 2048L * 1024, 1.f);
}

// Round 6
// 334.142 us; speedup vs baseline: 1.0286x; 1.0227x over previous
//
#include <hip/hip_runtime.h>
#include <hip/hip_bf16.h>

typedef __attribute__((ext_vector_type(8))) short short8;
typedef __attribute__((ext_vector_type(4))) float f32x4;

__device__ inline float b2f(unsigned short u) {
    union { unsigned int i; float f; } c; c.i = ((unsigned int)u) << 16; return c.f;
}
__device__ inline unsigned short f2b(float f) {
    __hip_bfloat16 h = __float2bfloat16(f);
    return *reinterpret_cast<unsigned short*>(&h);
}

// async global->LDS, 16 B per lane; LDS dest = wave-uniform base + lane*16
__device__ inline void gl_lds16(const unsigned short* g, unsigned short* ldsbase) {
    __builtin_amdgcn_global_load_lds(
        (const __attribute__((address_space(1))) unsigned int*)(g),
        (__attribute__((address_space(3))) unsigned int*)(ldsbase),
        16, 0, 0);
}

// ---- merged prep: weights transpose/convert + x convert + bvo, ONE dispatch ----
__global__ __launch_bounds__(256) void prep(
    const float* __restrict__ x,
    const float* __restrict__ Wq, const float* __restrict__ Wk,
    const float* __restrict__ Wo, const float* __restrict__ Wv,
    const float* __restrict__ bv, const float* __restrict__ bo,
    unsigned short* __restrict__ xb,
    unsigned short* __restrict__ Wqt, unsigned short* __restrict__ Wkt,
    unsigned short* __restrict__ Wot, unsigned short* __restrict__ Wvb,
    float* __restrict__ bvo)
{
    const int z = blockIdx.z;
    const int t = threadIdx.x;
    __shared__ float tile[32][33];

    if (z < 3) {
        const float* src = z == 0 ? Wq : z == 1 ? Wk : Wo;
        unsigned short* dst = z == 0 ? Wqt : z == 1 ? Wkt : Wot;
        const int c0 = blockIdx.x * 32, r0 = blockIdx.y * 32;
        const int tx = t & 31, ty = t >> 5;
        #pragma unroll
        for (int i = ty; i < 32; i += 8)
            tile[i][tx] = src[(long)(r0 + i) * 1024 + c0 + tx];
        __syncthreads();
        #pragma unroll
        for (int i = ty; i < 32; i += 8)
            dst[(long)(c0 + i) * 1024 + r0 + tx] = f2b(tile[tx][i]);
        return;
    }
    if (z == 3) {
        const int i = (blockIdx.y * 32 + blockIdx.x) * 256 + t;
        float4 v = ((const float4*)Wv)[i];
        union { unsigned short u[4]; unsigned long long ll; } p;
        p.u[0] = f2b(v.x); p.u[1] = f2b(v.y); p.u[2] = f2b(v.z); p.u[3] = f2b(v.w);
        ((unsigned long long*)Wvb)[i] = p.ll;
        return;
    }
    if (z < 6) {
        const int bl = (z - 4) * 1024 + blockIdx.y * 32 + blockIdx.x;
        #pragma unroll
        for (int k = 0; k < 4; k++) {
            const int i = bl * 1024 + k * 256 + t;
            float4 v = ((const float4*)x)[i];
            union { unsigned short u[4]; unsigned long long ll; } p;
            p.u[0] = f2b(v.x); p.u[1] = f2b(v.y); p.u[2] = f2b(v.z); p.u[3] = f2b(v.w);
            ((unsigned long long*)xb)[i] = p.ll;
        }
        return;
    }
    // z == 6: bvo. Only y==0 blocks work; block x handles n in [x*32, x*32+32).
    if (blockIdx.y != 0) return;
    const int tx = t & 31, ty = t >> 5;
    const int n = blockIdx.x * 32 + tx;
    float acc = 0.f;
    #pragma unroll 4
    for (int j = 0; j < 128; j++) {
        const int k = ty * 128 + j;
        acc += Wo[(long)k * 1024 + n] * bv[k];
    }
    float* red = &tile[0][0];  // reuse: 8x32 floats
    red[ty * 32 + tx] = acc;
    __syncthreads();
    if (ty == 0) {
        float s = 0.f;
        #pragma unroll
        for (int j = 0; j < 8; j++) s += red[j * 32 + tx];
        bvo[n] = s + bo[n];
    }
}

// ---- 128-tile K-loop body (gemm128) ----
#define TILE_KLOOP(As, Bs, gA, lda, gB, ldb, Keff) \
    for (int k0 = 0; k0 < (Keff); k0 += 64) { \
        _Pragma("unroll") for (int p = 0; p < 2; p++) \
            _Pragma("unroll") for (int h = 0; h < 2; h++) { \
                gl_lds16((gA) + (long)h * 16 * (lda) + k0 + p * 32, \
                         &(As)[p * 4096 + (w * 32 + h * 16) * 32]); \
                gl_lds16((gB) + (long)h * 16 * (ldb) + k0 + p * 32, \
                         &(Bs)[p * 4096 + (w * 32 + h * 16) * 32]); \
            } \
        __syncthreads(); \
        _Pragma("unroll") for (int p = 0; p < 2; p++) { \
            short8 af[4], bfr[4]; \
            _Pragma("unroll") for (int mi = 0; mi < 4; mi++) \
                af[mi] = *(const short8*)&(As)[p * 4096 + (wr * 64 + mi * 16 + lrow) * 32 + quad * 8]; \
            _Pragma("unroll") for (int ni = 0; ni < 4; ni++) \
                bfr[ni] = *(const short8*)&(Bs)[p * 4096 + (wc * 64 + ni * 16 + lrow) * 32 + quad * 8]; \
            _Pragma("unroll") for (int mi = 0; mi < 4; mi++) \
                _Pragma("unroll") for (int ni = 0; ni < 4; ni++) \
                    acc[mi][ni] = __builtin_amdgcn_mfma_f32_16x16x32_bf16( \
                        af[mi], bfr[ni], acc[mi][ni], 0, 0, 0); \
        } \
        __syncthreads(); \
    }

#define TILE_DECLS \
    const int t = threadIdx.x, lane = t & 63, w = t >> 6; \
    const int wr = w >> 1, wc = w & 1; \
    const int lrow = lane & 15, quad = lane >> 4; \
    f32x4 acc[4][4]; \
    _Pragma("unroll") for (int i = 0; i < 4; i++) \
        _Pragma("unroll") for (int j = 0; j < 4; j++) \
            acc[i][j] = (f32x4){0.f, 0.f, 0.f, 0.f};

template<bool TRI, bool KCAUSAL, int OMODE>
__global__ __launch_bounds__(256) void gemm128(
    const unsigned short* __restrict__ A, const unsigned short* __restrict__ Bt,
    const float* __restrict__ bias, void* __restrict__ Cv,
    int K, int lda, int ldb, int ldc, long sA, long sB, long sC, float scale)
{
    __shared__ __attribute__((aligned(16))) unsigned short As[2 * 128 * 32];
    __shared__ __attribute__((aligned(16))) unsigned short Bs[2 * 128 * 32];
    int bm, bn, bz;
    if (TRI) {
        // heavy-first: reverse the triangular index so large-K tiles launch first
        const int q = gridDim.x - 1 - blockIdx.x;
        bm = (int)((sqrtf(8.f * q + 1.f) - 1.f) * 0.5f);
        while ((bm + 1) * (bm + 2) / 2 <= q) bm++;
        while (bm * (bm + 1) / 2 > q) bm--;
        bn = q - bm * (bm + 1) / 2;
        bz = blockIdx.y;
    } else {
        bm = KCAUSAL ? (gridDim.x - 1 - blockIdx.x) : blockIdx.x;
        bn = blockIdx.y; bz = blockIdx.z;
    }
    A  += (long)bz * sA;
    Bt += (long)bz * sB;
    const int m0 = bm * 128, n0 = bn * 128;

    TILE_DECLS

    const int Keff = KCAUSAL ? ((bm + 1) * 128 < K ? (bm + 1) * 128 : K) : K;
    const unsigned short* gA = A  + (long)(m0 + w * 32 + (lane >> 2)) * lda + (lane & 3) * 8;
    const unsigned short* gB = Bt + (long)(n0 + w * 32 + (lane >> 2)) * ldb + (lane & 3) * 8;
    TILE_KLOOP(As, Bs, gA, lda, gB, ldb, Keff)

    #pragma unroll
    for (int mi = 0; mi < 4; mi++) {
        const int m = m0 + wr * 64 + mi * 16 + quad * 4;
        #pragma unroll
        for (int ni = 0; ni < 4; ni++) {
            const int n = n0 + wc * 64 + ni * 16 + lrow;
            const float bvl = bias ? bias[n] : 0.f;
            #pragma unroll
            for (int rg = 0; rg < 4; rg++) {
                const float val = acc[mi][ni][rg] * scale + bvl;
                if (OMODE == 1)
                    ((float*)Cv)[(long)bz * sC + (long)(m + rg) * ldc + n] = val;
                else
                    ((unsigned short*)Cv)[(long)bz * sC + (long)(m + rg) * ldc + n] = f2b(val);
            }
        }
    }
}

// Fused QKV projection, r-FUSED: one block stages the A-tile ONCE per K-step
// and runs it against all three B-panels (Wq^T, Wk^T, Wvo^T) -> 96 MFMA per
// staged A-tile instead of 32. LDS = A + 3xB = 64 KB (2 blocks/CU); grid 512
// = exactly co-resident. Epilogue pool aliases As+Bs0 after the K-loop.
__global__ __launch_bounds__(256, 2) void qkv_proj(
    const unsigned short* __restrict__ A,
    const unsigned short* __restrict__ Wqt, const unsigned short* __restrict__ Wkt,
    const unsigned short* __restrict__ Wvot,
    const float* __restrict__ bq, const float* __restrict__ bk,
    unsigned short* __restrict__ Q, unsigned short* __restrict__ Km,
    unsigned short* __restrict__ Vot)
{
    __shared__ __attribute__((aligned(16))) unsigned short smem[32768];  // 64 KiB
    unsigned short* As  = smem;
    unsigned short* Bs0 = smem + 8192;
    unsigned short* Bs1 = smem + 16384;
    unsigned short* Bs2 = smem + 24576;
    unsigned short* pool = smem;  // epilogue alias (32 KiB)

    const int bid = blockIdx.x;
    const int bnn = bid & 7, bm = bid >> 3;   // bnn-fastest: 8 consecutive blocks share A
    const int m0 = bm * 128, n0 = bnn * 128;

    const int t = threadIdx.x, lane = t & 63, w = t >> 6;
    const int wr = w >> 1, wc = w & 1;
    const int lrow = lane & 15, quad = lane >> 4;

    f32x4 accQ[4][4], accK[4][4], accV[4][4];
    #pragma unroll
    for (int i = 0; i < 4; i++)
        #pragma unroll
        for (int j = 0; j < 4; j++) {
            accQ[i][j] = (f32x4){0.f, 0.f, 0.f, 0.f};
            accK[i][j] = (f32x4){0.f, 0.f, 0.f, 0.f};
            accV[i][j] = (f32x4){0.f, 0.f, 0.f, 0.f};
        }

    const long rowA = (long)(m0 + w * 32 + (lane >> 2)) * 1024 + (lane & 3) * 8;
    const long rowB = (long)(n0 + w * 32 + (lane >> 2)) * 1024 + (lane & 3) * 8;
    const unsigned short* gA  = A    + rowA;
    const unsigned short* gB0 = Wqt  + rowB;
    const unsigned short* gB1 = Wkt  + rowB;
    const unsigned short* gB2 = Wvot + rowB;

    for (int k0 = 0; k0 < 1024; k0 += 64) {
        #pragma unroll
        for (int p = 0; p < 2; p++)
            #pragma unroll
            for (int h = 0; h < 2; h++) {
                const int ldst = p * 4096 + (w * 32 + h * 16) * 32;
                const long gofs = (long)h * 16 * 1024 + k0 + p * 32;
                gl_lds16(gA  + gofs, &As[ldst]);
                gl_lds16(gB0 + gofs, &Bs0[ldst]);
                gl_lds16(gB1 + gofs, &Bs1[ldst]);
                gl_lds16(gB2 + gofs, &Bs2[ldst]);
            }
        __syncthreads();
        #pragma unroll
        for (int p = 0; p < 2; p++) {
            short8 af[4], bfr[4];
            #pragma unroll
            for (int mi = 0; mi < 4; mi++)
                af[mi] = *(const short8*)&As[p * 4096 + (wr * 64 + mi * 16 + lrow) * 32 + quad * 8];
            // Q panel
            #pragma unroll
            for (int ni = 0; ni < 4; ni++)
                bfr[ni] = *(const short8*)&Bs0[p * 4096 + (wc * 64 + ni * 16 + lrow) * 32 + quad * 8];
            #pragma unroll
            for (int mi = 0; mi < 4; mi++)
                #pragma unroll
                for (int ni = 0; ni < 4; ni++)
                    accQ[mi][ni] = __builtin_amdgcn_mfma_f32_16x16x32_bf16(
                        af[mi], bfr[ni], accQ[mi][ni], 0, 0, 0);
            // K panel
            #pragma unroll
            for (int ni = 0; ni < 4; ni++)
                bfr[ni] = *(const short8*)&Bs1[p * 4096 + (wc * 64 + ni * 16 + lrow) * 32 + quad * 8];
            #pragma unroll
            for (int mi = 0; mi < 4; mi++)
                #pragma unroll
                for (int ni = 0; ni < 4; ni++)
                    accK[mi][ni] = __builtin_amdgcn_mfma_f32_16x16x32_bf16(
                        af[mi], bfr[ni], accK[mi][ni], 0, 0, 0);
            // V panel
            #pragma unroll
            for (int ni = 0; ni < 4; ni++)
                bfr[ni] = *(const short8*)&Bs2[p * 4096 + (wc * 64 + ni * 16 + lrow) * 32 + quad * 8];
            #pragma unroll
            for (int mi = 0; mi < 4; mi++)
                #pragma unroll
                for (int ni = 0; ni < 4; ni++)
                    accV[mi][ni] = __builtin_amdgcn_mfma_f32_16x16x32_bf16(
                        af[mi], bfr[ni], accV[mi][ni], 0, 0, 0);
        }
        __syncthreads();
    }
    // K-loop's final sync: all LDS reads done -> pool (As+Bs0 alias) reusable

    // --- Q epilogue (coalesced via pool) ---
    #pragma unroll
    for (int mi = 0; mi < 4; mi++)
        #pragma unroll
        for (int ni = 0; ni < 4; ni++) {
            const int n_l = wc * 64 + ni * 16 + lrow;
            const float bvl = bq[n0 + n_l];
            #pragma unroll
            for (int rg = 0; rg < 4; rg++) {
                const int m_l = wr * 64 + mi * 16 + quad * 4 + rg;
                pool[m_l * 128 + n_l] = f2b(accQ[mi][ni][rg] + bvl);
            }
        }
    __syncthreads();
    #pragma unroll
    for (int it = 0; it < 8; it++) {
        const int idx = it * 256 + t;
        const int m_l = idx >> 4, c = idx & 15;
        short8 v = *(const short8*)&pool[m_l * 128 + c * 8];
        *(short8*)&Q[(long)(m0 + m_l) * 1024 + n0 + c * 8] = v;
    }
    __syncthreads();

    // --- K epilogue ---
    #pragma unroll
    for (int mi = 0; mi < 4; mi++)
        #pragma unroll
        for (int ni = 0; ni < 4; ni++) {
            const int n_l = wc * 64 + ni * 16 + lrow;
            const float bvl = bk[n0 + n_l];
            #pragma unroll
            for (int rg = 0; rg < 4; rg++) {
                const int m_l = wr * 64 + mi * 16 + quad * 4 + rg;
                pool[m_l * 128 + n_l] = f2b(accK[mi][ni][rg] + bvl);
            }
        }
    __syncthreads();
    #pragma unroll
    for (int it = 0; it < 8; it++) {
        const int idx = it * 256 + t;
        const int m_l = idx >> 4, c = idx & 15;
        short8 v = *(const short8*)&pool[m_l * 128 + c * 8];
        *(short8*)&Km[(long)(m0 + m_l) * 1024 + n0 + c * 8] = v;
    }
    __syncthreads();

    // --- Vot epilogue (transposed, XOR-swizzled pool) ---
    #pragma unroll
    for (int mi = 0; mi < 4; mi++)
        #pragma unroll
        for (int ni = 0; ni < 4; ni++) {
            const int n_l = wc * 64 + ni * 16 + lrow;
            const int mb = wr * 64 + mi * 16 + quad * 4;
            union { unsigned short u[4]; unsigned long long ll; } pk;
            #pragma unroll
            for (int rg = 0; rg < 4; rg++) pk.u[rg] = f2b(accV[mi][ni][rg]);
            *(unsigned long long*)&pool[n_l * 128 + (mb ^ ((n_l & 15) << 3))] = pk.ll;
        }
    __syncthreads();
    #pragma unroll
    for (int it = 0; it < 8; it++) {
        const int idx = it * 256 + t;
        const int n_l = idx >> 4, c = idx & 15;
        short8 v = *(const short8*)&pool[n_l * 128 + ((c * 8) ^ ((n_l & 15) << 3))];
        *(short8*)&Vot[(long)(n0 + n_l) * 8192 + m0 + c * 8] = v;
    }
}

// Single-pass causal row softmax, 128-granular padding (PV uses 128-tile K cap).
// grid 2048: block i handles row i of all 4 batches.
__global__ __launch_bounds__(256) void softmax_causal(unsigned short* __restrict__ S)
{
    const int i = blockIdx.x;
    const int t = threadIdx.x;
    const int padded = ((i >> 7) + 1) << 7;
    const int j0 = t * 8;
    const bool active = j0 < padded;

    __shared__ float red[4];

    for (int b = 0; b < 4; b++) {
        unsigned short* base = S + ((long)b * 2048 + i) * 2048;

        float v[8];
        if (active) {
            short8 s8 = *(const short8*)(base + j0);
            #pragma unroll
            for (int jj = 0; jj < 8; jj++)
                v[jj] = (j0 + jj <= i) ? b2f((unsigned short)s8[jj]) : -3.0e38f;
        } else {
            #pragma unroll
            for (int jj = 0; jj < 8; jj++) v[jj] = -3.0e38f;
        }

        float lmax = v[0];
        #pragma unroll
        for (int jj = 1; jj < 8; jj++) lmax = fmaxf(lmax, v[jj]);
        #pragma unroll
        for (int off = 32; off > 0; off >>= 1) lmax = fmaxf(lmax, __shfl_xor(lmax, off, 64));
        if ((t & 63) == 0) red[t >> 6] = lmax;
        __syncthreads();
        const float gmax = fmaxf(fmaxf(red[0], red[1]), fmaxf(red[2], red[3]));
        __syncthreads();

        float lsum = 0.f;
        #pragma unroll
        for (int jj = 0; jj < 8; jj++) {
            v[jj] = (v[jj] > -1.0e37f) ? __expf(v[jj] - gmax) : 0.f;
            lsum += v[jj];
        }
        #pragma unroll
        for (int off = 32; off > 0; off >>= 1) lsum += __shfl_xor(lsum, off, 64);
        if ((t & 63) == 0) red[t >> 6] = lsum;
        __syncthreads();
        const float inv = 1.0f / (red[0] + red[1] + red[2] + red[3]);

        if (active) {
            short8 p8;
            #pragma unroll
            for (int jj = 0; jj < 8; jj++) p8[jj] = (short)f2b(v[jj] * inv);
            *(short8*)(base + j0) = p8;
        }
        __syncthreads();  // red[] reused next batch
    }
}

extern "C" void kernel_launch(void* const* d_in, const int* in_sizes, int n_in,
                              void* d_out, int out_size, void* d_ws, size_t ws_size,
                              hipStream_t stream)
{
    const float* x  = (const float*)d_in[0];
    const float* Wq = (const float*)d_in[2];
    const float* bq = (const float*)d_in[3];
    const float* Wk = (const float*)d_in[4];
    const float* bk = (const float*)d_in[5];
    const float* Wv = (const float*)d_in[6];
    const float* bv = (const float*)d_in[7];
    const float* Wo = (const float*)d_in[8];
    const float* bo = (const float*)d_in[9];

    unsigned short* ws = (unsigned short*)d_ws;
    const long XSZ = 8192L * 1024;
    const long WSZ = 1024L * 1024;
    unsigned short* xb   = ws;                // [8192,1024] bf16
    unsigned short* Wqt  = ws + XSZ;          // Wq^T bf16
    unsigned short* Wkt  = Wqt + WSZ;         // Wk^T bf16
    unsigned short* Wot  = Wkt + WSZ;         // Wo^T bf16
    unsigned short* Wvb  = Wot + WSZ;         // Wv bf16 (plain)
    unsigned short* Wvot = Wvb + WSZ;         // (Wv@Wo)^T bf16
    unsigned short* Q    = Wvot + WSZ;        // [8192,1024]
    unsigned short* Km   = Q + XSZ;           // [8192,1024]
    unsigned short* Vot  = Km + XSZ;          // [1024,8192] = (x@Wvo)^T
    unsigned short* S    = Vot + XSZ;         // [4][2048,2048] (S -> P in place)
    float*          bvo  = (float*)(S + 4L * 2048 * 2048);   // [1024] fp32

    const dim3 blk(256);

    // merged prep: weights + x convert + bvo, one dispatch
    prep<<<dim3(32, 32, 7), blk, 0, stream>>>(
        x, Wq, Wk, Wo, Wv, bv, bo, xb, Wqt, Wkt, Wot, Wvb, bvo);

    // Wvo^T = Wo^T @ Wv^T
    gemm128<false, false, 0><<<dim3(8, 8, 1), blk, 0, stream>>>(
        Wot, Wvb, nullptr, Wvot, 1024, 1024, 1024, 1024, 0, 0, 0, 1.f);

    // fused QKV projection (r-fused: A staged once for 3 B-panels)
    qkv_proj<<<dim3(512), blk, 0, stream>>>(
        xb, Wqt, Wkt, Wvot, bq, bk, Q, Km, Vot);

    // S = Q K^T / sqrt(D), triangular grid, heavy-first
    gemm128<true, false, 0><<<dim3(136, 4), blk, 0, stream>>>(
        Q, Km, nullptr, S, 1024, 1024, 1024, 2048,
        2048L * 1024, 2048L * 1024, 2048L * 2048, 0.03125f);

    softmax_causal<<<dim3(2048), blk, 0, stream>>>(S);

    // out = P @ Vo + bvo  (fp32, final output), causal K cap, heavy tiles first
    gemm128<false, true, 1><<<dim3(16, 8, 4), blk, 0, stream>>>(
        S, Vot, bvo, (float*)d_out, 2048, 2048, 8192, 1024,
        2048L * 2048, 2048, 2048L * 1024, 1.f);
}

// Round 7
// 326.916 us; speedup vs baseline: 1.0513x; 1.0221x over previous
//
#include <hip/hip_runtime.h>
#include <hip/hip_bf16.h>

typedef __attribute__((ext_vector_type(8))) short short8;
typedef __attribute__((ext_vector_type(4))) float f32x4;

__device__ inline float b2f(unsigned short u) {
    union { unsigned int i; float f; } c; c.i = ((unsigned int)u) << 16; return c.f;
}
__device__ inline unsigned short f2b(float f) {
    __hip_bfloat16 h = __float2bfloat16(f);
    return *reinterpret_cast<unsigned short*>(&h);
}

// async global->LDS, 16 B per lane; LDS dest = wave-uniform base + lane*16
__device__ inline void gl_lds16(const unsigned short* g, unsigned short* ldsbase) {
    __builtin_amdgcn_global_load_lds(
        (const __attribute__((address_space(1))) unsigned int*)(g),
        (__attribute__((address_space(3))) unsigned int*)(ldsbase),
        16, 0, 0);
}

// ---- merged prep: weights transpose/convert + x convert + bvo, ONE dispatch ----
__global__ __launch_bounds__(256) void prep(
    const float* __restrict__ x,
    const float* __restrict__ Wq, const float* __restrict__ Wk,
    const float* __restrict__ Wo, const float* __restrict__ Wv,
    const float* __restrict__ bv, const float* __restrict__ bo,
    unsigned short* __restrict__ xb,
    unsigned short* __restrict__ Wqt, unsigned short* __restrict__ Wkt,
    unsigned short* __restrict__ Wot, unsigned short* __restrict__ Wvb,
    float* __restrict__ bvo)
{
    const int z = blockIdx.z;
    const int t = threadIdx.x;
    __shared__ float tile[32][33];

    if (z < 3) {
        const float* src = z == 0 ? Wq : z == 1 ? Wk : Wo;
        unsigned short* dst = z == 0 ? Wqt : z == 1 ? Wkt : Wot;
        const int c0 = blockIdx.x * 32, r0 = blockIdx.y * 32;
        const int tx = t & 31, ty = t >> 5;
        #pragma unroll
        for (int i = ty; i < 32; i += 8)
            tile[i][tx] = src[(long)(r0 + i) * 1024 + c0 + tx];
        __syncthreads();
        #pragma unroll
        for (int i = ty; i < 32; i += 8)
            dst[(long)(c0 + i) * 1024 + r0 + tx] = f2b(tile[tx][i]);
        return;
    }
    if (z == 3) {
        const int i = (blockIdx.y * 32 + blockIdx.x) * 256 + t;
        float4 v = ((const float4*)Wv)[i];
        union { unsigned short u[4]; unsigned long long ll; } p;
        p.u[0] = f2b(v.x); p.u[1] = f2b(v.y); p.u[2] = f2b(v.z); p.u[3] = f2b(v.w);
        ((unsigned long long*)Wvb)[i] = p.ll;
        return;
    }
    if (z < 6) {
        const int bl = (z - 4) * 1024 + blockIdx.y * 32 + blockIdx.x;
        #pragma unroll
        for (int k = 0; k < 4; k++) {
            const int i = bl * 1024 + k * 256 + t;
            float4 v = ((const float4*)x)[i];
            union { unsigned short u[4]; unsigned long long ll; } p;
            p.u[0] = f2b(v.x); p.u[1] = f2b(v.y); p.u[2] = f2b(v.z); p.u[3] = f2b(v.w);
            ((unsigned long long*)xb)[i] = p.ll;
        }
        return;
    }
    // z == 6: bvo. Only y==0 blocks work; block x handles n in [x*32, x*32+32).
    if (blockIdx.y != 0) return;
    const int tx = t & 31, ty = t >> 5;
    const int n = blockIdx.x * 32 + tx;
    float acc = 0.f;
    #pragma unroll 4
    for (int j = 0; j < 128; j++) {
        const int k = ty * 128 + j;
        acc += Wo[(long)k * 1024 + n] * bv[k];
    }
    float* red = &tile[0][0];  // reuse: 8x32 floats
    red[ty * 32 + tx] = acc;
    __syncthreads();
    if (ty == 0) {
        float s = 0.f;
        #pragma unroll
        for (int j = 0; j < 8; j++) s += red[j * 32 + tx];
        bvo[n] = s + bo[n];
    }
}

// ---- 128-tile K-loop body (gemm128: Wvo prep only) ----
#define TILE_KLOOP(As, Bs, gA, lda, gB, ldb, Keff) \
    for (int k0 = 0; k0 < (Keff); k0 += 64) { \
        _Pragma("unroll") for (int p = 0; p < 2; p++) \
            _Pragma("unroll") for (int h = 0; h < 2; h++) { \
                gl_lds16((gA) + (long)h * 16 * (lda) + k0 + p * 32, \
                         &(As)[p * 4096 + (w * 32 + h * 16) * 32]); \
                gl_lds16((gB) + (long)h * 16 * (ldb) + k0 + p * 32, \
                         &(Bs)[p * 4096 + (w * 32 + h * 16) * 32]); \
            } \
        __syncthreads(); \
        _Pragma("unroll") for (int p = 0; p < 2; p++) { \
            short8 af[4], bfr[4]; \
            _Pragma("unroll") for (int mi = 0; mi < 4; mi++) \
                af[mi] = *(const short8*)&(As)[p * 4096 + (wr * 64 + mi * 16 + lrow) * 32 + quad * 8]; \
            _Pragma("unroll") for (int ni = 0; ni < 4; ni++) \
                bfr[ni] = *(const short8*)&(Bs)[p * 4096 + (wc * 64 + ni * 16 + lrow) * 32 + quad * 8]; \
            _Pragma("unroll") for (int mi = 0; mi < 4; mi++) \
                _Pragma("unroll") for (int ni = 0; ni < 4; ni++) \
                    acc[mi][ni] = __builtin_amdgcn_mfma_f32_16x16x32_bf16( \
                        af[mi], bfr[ni], acc[mi][ni], 0, 0, 0); \
        } \
        __syncthreads(); \
    }

#define TILE_DECLS \
    const int t = threadIdx.x, lane = t & 63, w = t >> 6; \
    const int wr = w >> 1, wc = w & 1; \
    const int lrow = lane & 15, quad = lane >> 4; \
    f32x4 acc[4][4]; \
    _Pragma("unroll") for (int i = 0; i < 4; i++) \
        _Pragma("unroll") for (int j = 0; j < 4; j++) \
            acc[i][j] = (f32x4){0.f, 0.f, 0.f, 0.f};

__global__ __launch_bounds__(256) void gemm128(
    const unsigned short* __restrict__ A, const unsigned short* __restrict__ Bt,
    unsigned short* __restrict__ C)
{
    __shared__ __attribute__((aligned(16))) unsigned short As[2 * 128 * 32];
    __shared__ __attribute__((aligned(16))) unsigned short Bs[2 * 128 * 32];
    const int m0 = blockIdx.x * 128, n0 = blockIdx.y * 128;

    TILE_DECLS

    const unsigned short* gA = A  + (long)(m0 + w * 32 + (lane >> 2)) * 1024 + (lane & 3) * 8;
    const unsigned short* gB = Bt + (long)(n0 + w * 32 + (lane >> 2)) * 1024 + (lane & 3) * 8;
    TILE_KLOOP(As, Bs, gA, 1024, gB, 1024, 1024)

    #pragma unroll
    for (int mi = 0; mi < 4; mi++) {
        const int m = m0 + wr * 64 + mi * 16 + quad * 4;
        #pragma unroll
        for (int ni = 0; ni < 4; ni++) {
            const int n = n0 + wc * 64 + ni * 16 + lrow;
            #pragma unroll
            for (int rg = 0; rg < 4; rg++)
                C[(long)(m + rg) * 1024 + n] = f2b(acc[mi][ni][rg]);
        }
    }
}

// ---- shared 2-B-panel machinery (A staged once per K-step, 2 output tiles) ----
#define TILE2_DECLS \
    const int t = threadIdx.x, lane = t & 63, w = t >> 6; \
    const int wr = w >> 1, wc = w & 1; \
    const int lrow = lane & 15, quad = lane >> 4; \
    f32x4 acc0[4][4], acc1[4][4]; \
    _Pragma("unroll") for (int i = 0; i < 4; i++) \
        _Pragma("unroll") for (int j = 0; j < 4; j++) { \
            acc0[i][j] = (f32x4){0.f, 0.f, 0.f, 0.f}; \
            acc1[i][j] = (f32x4){0.f, 0.f, 0.f, 0.f}; \
        }

#define TILE2_KLOOP(gA, lda, gB0, gB1, ldb, Keff) \
    for (int k0 = 0; k0 < (Keff); k0 += 64) { \
        _Pragma("unroll") for (int p = 0; p < 2; p++) \
            _Pragma("unroll") for (int h = 0; h < 2; h++) { \
                const int ldst = p * 4096 + (w * 32 + h * 16) * 32; \
                const long gofs = (long)h * 16 * (lda) + k0 + p * 32; \
                const long gofsB = (long)h * 16 * (ldb) + k0 + p * 32; \
                gl_lds16((gA)  + gofs,  &As[ldst]); \
                gl_lds16((gB0) + gofsB, &Bs0[ldst]); \
                gl_lds16((gB1) + gofsB, &Bs1[ldst]); \
            } \
        __syncthreads(); \
        _Pragma("unroll") for (int p = 0; p < 2; p++) { \
            short8 af[4], bfr[4]; \
            _Pragma("unroll") for (int mi = 0; mi < 4; mi++) \
                af[mi] = *(const short8*)&As[p * 4096 + (wr * 64 + mi * 16 + lrow) * 32 + quad * 8]; \
            _Pragma("unroll") for (int ni = 0; ni < 4; ni++) \
                bfr[ni] = *(const short8*)&Bs0[p * 4096 + (wc * 64 + ni * 16 + lrow) * 32 + quad * 8]; \
            _Pragma("unroll") for (int mi = 0; mi < 4; mi++) \
                _Pragma("unroll") for (int ni = 0; ni < 4; ni++) \
                    acc0[mi][ni] = __builtin_amdgcn_mfma_f32_16x16x32_bf16( \
                        af[mi], bfr[ni], acc0[mi][ni], 0, 0, 0); \
            _Pragma("unroll") for (int ni = 0; ni < 4; ni++) \
                bfr[ni] = *(const short8*)&Bs1[p * 4096 + (wc * 64 + ni * 16 + lrow) * 32 + quad * 8]; \
            _Pragma("unroll") for (int mi = 0; mi < 4; mi++) \
                _Pragma("unroll") for (int ni = 0; ni < 4; ni++) \
                    acc1[mi][ni] = __builtin_amdgcn_mfma_f32_16x16x32_bf16( \
                        af[mi], bfr[ni], acc1[mi][ni], 0, 0, 0); \
        } \
        __syncthreads(); \
    }

// QK^T with triangular PAIR grid: 72 pairs/batch; pair bp covers bn={2bp,2bp+1}.
// Overflow tile (bn=bm+1, even bm) is strictly above the diagonal: written
// unconditionally, never read by softmax (padded<=...) nor PV (Keff cap).
__global__ __launch_bounds__(256, 2) void gemm_qk2(
    const unsigned short* __restrict__ Q, const unsigned short* __restrict__ Km,
    unsigned short* __restrict__ S)
{
    __shared__ __attribute__((aligned(16))) unsigned short As[8192];
    __shared__ __attribute__((aligned(16))) unsigned short Bs0[8192];
    __shared__ __attribute__((aligned(16))) unsigned short Bs1[8192];

    const int q = 71 - blockIdx.x;  // heavy-first
    int tq = (int)sqrtf((float)q);
    while (tq * tq + tq > q) tq--;
    while ((tq + 1) * (tq + 1) + (tq + 1) <= q) tq++;
    int bm, bp;
    if (q >= (tq + 1) * (tq + 1)) { bm = 2 * tq + 1; bp = q - (tq + 1) * (tq + 1); }
    else                          { bm = 2 * tq;     bp = q - (tq * tq + tq); }
    const int bz = blockIdx.y;
    const unsigned short* A  = Q  + (long)bz * 2048 * 1024;
    const unsigned short* Bt = Km + (long)bz * 2048 * 1024;
    const int m0 = bm * 128, n0 = bp * 256;

    TILE2_DECLS

    const unsigned short* gA  = A  + (long)(m0 + w * 32 + (lane >> 2)) * 1024 + (lane & 3) * 8;
    const unsigned short* gB0 = Bt + (long)(n0 + w * 32 + (lane >> 2)) * 1024 + (lane & 3) * 8;
    const unsigned short* gB1 = gB0 + 128L * 1024;
    TILE2_KLOOP(gA, 1024, gB0, gB1, 1024, 1024)

    unsigned short* Sb = S + (long)bz * 2048 * 2048;
    #pragma unroll
    for (int mi = 0; mi < 4; mi++) {
        const int m = m0 + wr * 64 + mi * 16 + quad * 4;
        #pragma unroll
        for (int ni = 0; ni < 4; ni++) {
            const int nl = wc * 64 + ni * 16 + lrow;
            #pragma unroll
            for (int rg = 0; rg < 4; rg++) {
                Sb[(long)(m + rg) * 2048 + n0 + nl]       = f2b(acc0[mi][ni][rg] * 0.03125f);
                Sb[(long)(m + rg) * 2048 + n0 + 128 + nl] = f2b(acc1[mi][ni][rg] * 0.03125f);
            }
        }
    }
}

// PV with paired Vo panels: out = P @ Vo + bvo (fp32). A(S) staged once per
// K-step for 2 B-panels -> S read traffic halved, MFMA density doubled.
__global__ __launch_bounds__(256, 2) void gemm_pv2(
    const unsigned short* __restrict__ S, const unsigned short* __restrict__ Vot,
    const float* __restrict__ bvo, float* __restrict__ out)
{
    __shared__ __attribute__((aligned(16))) unsigned short As[8192];
    __shared__ __attribute__((aligned(16))) unsigned short Bs0[8192];
    __shared__ __attribute__((aligned(16))) unsigned short Bs1[8192];

    const int bm = 15 - (int)blockIdx.x;      // heavy (large Keff) first
    const int bn2 = blockIdx.y, bz = blockIdx.z;
    const unsigned short* A  = S   + (long)bz * 2048 * 2048;
    const unsigned short* Bt = Vot + (long)bz * 2048;
    const int m0 = bm * 128, n0 = bn2 * 256;
    const int Keff = (bm + 1) * 128;

    TILE2_DECLS

    const unsigned short* gA  = A  + (long)(m0 + w * 32 + (lane >> 2)) * 2048 + (lane & 3) * 8;
    const unsigned short* gB0 = Bt + (long)(n0 + w * 32 + (lane >> 2)) * 8192 + (lane & 3) * 8;
    const unsigned short* gB1 = gB0 + 128L * 8192;
    TILE2_KLOOP(gA, 2048, gB0, gB1, 8192, Keff)

    float* ob = out + (long)bz * 2048 * 1024;
    #pragma unroll
    for (int mi = 0; mi < 4; mi++) {
        const int m = m0 + wr * 64 + mi * 16 + quad * 4;
        #pragma unroll
        for (int ni = 0; ni < 4; ni++) {
            const int nl = wc * 64 + ni * 16 + lrow;
            const float bv0 = bvo[n0 + nl];
            const float bv1 = bvo[n0 + 128 + nl];
            #pragma unroll
            for (int rg = 0; rg < 4; rg++) {
                ob[(long)(m + rg) * 1024 + n0 + nl]       = acc0[mi][ni][rg] + bv0;
                ob[(long)(m + rg) * 1024 + n0 + 128 + nl] = acc1[mi][ni][rg] + bv1;
            }
        }
    }
}

// Fused QKV projection, r-FUSED: A-tile staged once per K-step for 3 B-panels.
__global__ __launch_bounds__(256, 2) void qkv_proj(
    const unsigned short* __restrict__ A,
    const unsigned short* __restrict__ Wqt, const unsigned short* __restrict__ Wkt,
    const unsigned short* __restrict__ Wvot,
    const float* __restrict__ bq, const float* __restrict__ bk,
    unsigned short* __restrict__ Q, unsigned short* __restrict__ Km,
    unsigned short* __restrict__ Vot)
{
    __shared__ __attribute__((aligned(16))) unsigned short smem[32768];  // 64 KiB
    unsigned short* As  = smem;
    unsigned short* Bs0 = smem + 8192;
    unsigned short* Bs1 = smem + 16384;
    unsigned short* Bs2 = smem + 24576;
    unsigned short* pool = smem;  // epilogue alias (32 KiB)

    const int bid = blockIdx.x;
    const int bnn = bid & 7, bm = bid >> 3;   // bnn-fastest: 8 consecutive blocks share A
    const int m0 = bm * 128, n0 = bnn * 128;

    const int t = threadIdx.x, lane = t & 63, w = t >> 6;
    const int wr = w >> 1, wc = w & 1;
    const int lrow = lane & 15, quad = lane >> 4;

    f32x4 accQ[4][4], accK[4][4], accV[4][4];
    #pragma unroll
    for (int i = 0; i < 4; i++)
        #pragma unroll
        for (int j = 0; j < 4; j++) {
            accQ[i][j] = (f32x4){0.f, 0.f, 0.f, 0.f};
            accK[i][j] = (f32x4){0.f, 0.f, 0.f, 0.f};
            accV[i][j] = (f32x4){0.f, 0.f, 0.f, 0.f};
        }

    const long rowA = (long)(m0 + w * 32 + (lane >> 2)) * 1024 + (lane & 3) * 8;
    const long rowB = (long)(n0 + w * 32 + (lane >> 2)) * 1024 + (lane & 3) * 8;
    const unsigned short* gA  = A    + rowA;
    const unsigned short* gB0 = Wqt  + rowB;
    const unsigned short* gB1 = Wkt  + rowB;
    const unsigned short* gB2 = Wvot + rowB;

    for (int k0 = 0; k0 < 1024; k0 += 64) {
        #pragma unroll
        for (int p = 0; p < 2; p++)
            #pragma unroll
            for (int h = 0; h < 2; h++) {
                const int ldst = p * 4096 + (w * 32 + h * 16) * 32;
                const long gofs = (long)h * 16 * 1024 + k0 + p * 32;
                gl_lds16(gA  + gofs, &As[ldst]);
                gl_lds16(gB0 + gofs, &Bs0[ldst]);
                gl_lds16(gB1 + gofs, &Bs1[ldst]);
                gl_lds16(gB2 + gofs, &Bs2[ldst]);
            }
        __syncthreads();
        #pragma unroll
        for (int p = 0; p < 2; p++) {
            short8 af[4], bfr[4];
            #pragma unroll
            for (int mi = 0; mi < 4; mi++)
                af[mi] = *(const short8*)&As[p * 4096 + (wr * 64 + mi * 16 + lrow) * 32 + quad * 8];
            #pragma unroll
            for (int ni = 0; ni < 4; ni++)
                bfr[ni] = *(const short8*)&Bs0[p * 4096 + (wc * 64 + ni * 16 + lrow) * 32 + quad * 8];
            #pragma unroll
            for (int mi = 0; mi < 4; mi++)
                #pragma unroll
                for (int ni = 0; ni < 4; ni++)
                    accQ[mi][ni] = __builtin_amdgcn_mfma_f32_16x16x32_bf16(
                        af[mi], bfr[ni], accQ[mi][ni], 0, 0, 0);
            #pragma unroll
            for (int ni = 0; ni < 4; ni++)
                bfr[ni] = *(const short8*)&Bs1[p * 4096 + (wc * 64 + ni * 16 + lrow) * 32 + quad * 8];
            #pragma unroll
            for (int mi = 0; mi < 4; mi++)
                #pragma unroll
                for (int ni = 0; ni < 4; ni++)
                    accK[mi][ni] = __builtin_amdgcn_mfma_f32_16x16x32_bf16(
                        af[mi], bfr[ni], accK[mi][ni], 0, 0, 0);
            #pragma unroll
            for (int ni = 0; ni < 4; ni++)
                bfr[ni] = *(const short8*)&Bs2[p * 4096 + (wc * 64 + ni * 16 + lrow) * 32 + quad * 8];
            #pragma unroll
            for (int mi = 0; mi < 4; mi++)
                #pragma unroll
                for (int ni = 0; ni < 4; ni++)
                    accV[mi][ni] = __builtin_amdgcn_mfma_f32_16x16x32_bf16(
                        af[mi], bfr[ni], accV[mi][ni], 0, 0, 0);
        }
        __syncthreads();
    }

    // --- Q epilogue (coalesced via pool) ---
    #pragma unroll
    for (int mi = 0; mi < 4; mi++)
        #pragma unroll
        for (int ni = 0; ni < 4; ni++) {
            const int n_l = wc * 64 + ni * 16 + lrow;
            const float bvl = bq[n0 + n_l];
            #pragma unroll
            for (int rg = 0; rg < 4; rg++) {
                const int m_l = wr * 64 + mi * 16 + quad * 4 + rg;
                pool[m_l * 128 + n_l] = f2b(accQ[mi][ni][rg] + bvl);
            }
        }
    __syncthreads();
    #pragma unroll
    for (int it = 0; it < 8; it++) {
        const int idx = it * 256 + t;
        const int m_l = idx >> 4, c = idx & 15;
        short8 v = *(const short8*)&pool[m_l * 128 + c * 8];
        *(short8*)&Q[(long)(m0 + m_l) * 1024 + n0 + c * 8] = v;
    }
    __syncthreads();

    // --- K epilogue ---
    #pragma unroll
    for (int mi = 0; mi < 4; mi++)
        #pragma unroll
        for (int ni = 0; ni < 4; ni++) {
            const int n_l = wc * 64 + ni * 16 + lrow;
            const float bvl = bk[n0 + n_l];
            #pragma unroll
            for (int rg = 0; rg < 4; rg++) {
                const int m_l = wr * 64 + mi * 16 + quad * 4 + rg;
                pool[m_l * 128 + n_l] = f2b(accK[mi][ni][rg] + bvl);
            }
        }
    __syncthreads();
    #pragma unroll
    for (int it = 0; it < 8; it++) {
        const int idx = it * 256 + t;
        const int m_l = idx >> 4, c = idx & 15;
        short8 v = *(const short8*)&pool[m_l * 128 + c * 8];
        *(short8*)&Km[(long)(m0 + m_l) * 1024 + n0 + c * 8] = v;
    }
    __syncthreads();

    // --- Vot epilogue (transposed, XOR-swizzled pool) ---
    #pragma unroll
    for (int mi = 0; mi < 4; mi++)
        #pragma unroll
        for (int ni = 0; ni < 4; ni++) {
            const int n_l = wc * 64 + ni * 16 + lrow;
            const int mb = wr * 64 + mi * 16 + quad * 4;
            union { unsigned short u[4]; unsigned long long ll; } pk;
            #pragma unroll
            for (int rg = 0; rg < 4; rg++) pk.u[rg] = f2b(accV[mi][ni][rg]);
            *(unsigned long long*)&pool[n_l * 128 + (mb ^ ((n_l & 15) << 3))] = pk.ll;
        }
    __syncthreads();
    #pragma unroll
    for (int it = 0; it < 8; it++) {
        const int idx = it * 256 + t;
        const int n_l = idx >> 4, c = idx & 15;
        short8 v = *(const short8*)&pool[n_l * 128 + ((c * 8) ^ ((n_l & 15) << 3))];
        *(short8*)&Vot[(long)(n0 + n_l) * 8192 + m0 + c * 8] = v;
    }
}

// Single-pass causal row softmax, 128-granular padding (PV uses 128-tile K cap).
__global__ __launch_bounds__(256) void softmax_causal(unsigned short* __restrict__ S)
{
    const int i = blockIdx.x;
    const int t = threadIdx.x;
    const int padded = ((i >> 7) + 1) << 7;
    const int j0 = t * 8;
    const bool active = j0 < padded;

    __shared__ float red[4];

    for (int b = 0; b < 4; b++) {
        unsigned short* base = S + ((long)b * 2048 + i) * 2048;

        float v[8];
        if (active) {
            short8 s8 = *(const short8*)(base + j0);
            #pragma unroll
            for (int jj = 0; jj < 8; jj++)
                v[jj] = (j0 + jj <= i) ? b2f((unsigned short)s8[jj]) : -3.0e38f;
        } else {
            #pragma unroll
            for (int jj = 0; jj < 8; jj++) v[jj] = -3.0e38f;
        }

        float lmax = v[0];
        #pragma unroll
        for (int jj = 1; jj < 8; jj++) lmax = fmaxf(lmax, v[jj]);
        #pragma unroll
        for (int off = 32; off > 0; off >>= 1) lmax = fmaxf(lmax, __shfl_xor(lmax, off, 64));
        if ((t & 63) == 0) red[t >> 6] = lmax;
        __syncthreads();
        const float gmax = fmaxf(fmaxf(red[0], red[1]), fmaxf(red[2], red[3]));
        __syncthreads();

        float lsum = 0.f;
        #pragma unroll
        for (int jj = 0; jj < 8; jj++) {
            v[jj] = (v[jj] > -1.0e37f) ? __expf(v[jj] - gmax) : 0.f;
            lsum += v[jj];
        }
        #pragma unroll
        for (int off = 32; off > 0; off >>= 1) lsum += __shfl_xor(lsum, off, 64);
        if ((t & 63) == 0) red[t >> 6] = lsum;
        __syncthreads();
        const float inv = 1.0f / (red[0] + red[1] + red[2] + red[3]);

        if (active) {
            short8 p8;
            #pragma unroll
            for (int jj = 0; jj < 8; jj++) p8[jj] = (short)f2b(v[jj] * inv);
            *(short8*)(base + j0) = p8;
        }
        __syncthreads();  // red[] reused next batch
    }
}

extern "C" void kernel_launch(void* const* d_in, const int* in_sizes, int n_in,
                              void* d_out, int out_size, void* d_ws, size_t ws_size,
                              hipStream_t stream)
{
    const float* x  = (const float*)d_in[0];
    const float* Wq = (const float*)d_in[2];
    const float* bq = (const float*)d_in[3];
    const float* Wk = (const float*)d_in[4];
    const float* bk = (const float*)d_in[5];
    const float* Wv = (const float*)d_in[6];
    const float* bv = (const float*)d_in[7];
    const float* Wo = (const float*)d_in[8];
    const float* bo = (const float*)d_in[9];

    unsigned short* ws = (unsigned short*)d_ws;
    const long XSZ = 8192L * 1024;
    const long WSZ = 1024L * 1024;
    unsigned short* xb   = ws;                // [8192,1024] bf16
    unsigned short* Wqt  = ws + XSZ;          // Wq^T bf16
    unsigned short* Wkt  = Wqt + WSZ;         // Wk^T bf16
    unsigned short* Wot  = Wkt + WSZ;         // Wo^T bf16
    unsigned short* Wvb  = Wot + WSZ;         // Wv bf16 (plain)
    unsigned short* Wvot = Wvb + WSZ;         // (Wv@Wo)^T bf16
    unsigned short* Q    = Wvot + WSZ;        // [8192,1024]
    unsigned short* Km   = Q + XSZ;           // [8192,1024]
    unsigned short* Vot  = Km + XSZ;          // [1024,8192] = (x@Wvo)^T
    unsigned short* S    = Vot + XSZ;         // [4][2048,2048] (S -> P in place)
    float*          bvo  = (float*)(S + 4L * 2048 * 2048);   // [1024] fp32

    const dim3 blk(256);

    // merged prep: weights + x convert + bvo, one dispatch
    prep<<<dim3(32, 32, 7), blk, 0, stream>>>(
        x, Wq, Wk, Wo, Wv, bv, bo, xb, Wqt, Wkt, Wot, Wvb, bvo);

    // Wvo^T = Wo^T @ Wv^T
    gemm128<<<dim3(8, 8), blk, 0, stream>>>(Wot, Wvb, Wvot);

    // fused QKV projection (r-fused: A staged once for 3 B-panels)
    qkv_proj<<<dim3(512), blk, 0, stream>>>(
        xb, Wqt, Wkt, Wvot, bq, bk, Q, Km, Vot);

    // S = Q K^T / sqrt(D), triangular pair grid (2 bn tiles per block)
    gemm_qk2<<<dim3(72, 4), blk, 0, stream>>>(Q, Km, S);

    softmax_causal<<<dim3(2048), blk, 0, stream>>>(S);

    // out = P @ Vo + bvo, paired Vo panels, causal K cap, heavy tiles first
    gemm_pv2<<<dim3(16, 4, 4), blk, 0, stream>>>(S, Vot, bvo, (float*)d_out);
}

// Round 8
// 326.619 us; speedup vs baseline: 1.0523x; 1.0009x over previous
//
#include <hip/hip_runtime.h>
#include <hip/hip_bf16.h>

typedef __attribute__((ext_vector_type(8))) short short8;
typedef __attribute__((ext_vector_type(4))) float f32x4;

__device__ inline float b2f(unsigned short u) {
    union { unsigned int i; float f; } c; c.i = ((unsigned int)u) << 16; return c.f;
}
__device__ inline unsigned short f2b(float f) {
    __hip_bfloat16 h = __float2bfloat16(f);
    return *reinterpret_cast<unsigned short*>(&h);
}

// async global->LDS, 16 B per lane; LDS dest = wave-uniform base + lane*16
__device__ inline void gl_lds16(const unsigned short* g, unsigned short* ldsbase) {
    __builtin_amdgcn_global_load_lds(
        (const __attribute__((address_space(1))) unsigned int*)(g),
        (__attribute__((address_space(3))) unsigned int*)(ldsbase),
        16, 0, 0);
}

// ---- merged prep: weights transpose/convert + x convert + bvo, ONE dispatch ----
__global__ __launch_bounds__(256) void prep(
    const float* __restrict__ x,
    const float* __restrict__ Wq, const float* __restrict__ Wk,
    const float* __restrict__ Wo, const float* __restrict__ Wv,
    const float* __restrict__ bv, const float* __restrict__ bo,
    unsigned short* __restrict__ xb,
    unsigned short* __restrict__ Wqt, unsigned short* __restrict__ Wkt,
    unsigned short* __restrict__ Wot, unsigned short* __restrict__ Wvb,
    float* __restrict__ bvo)
{
    const int z = blockIdx.z;
    const int t = threadIdx.x;
    __shared__ float tile[32][33];

    if (z < 3) {
        const float* src = z == 0 ? Wq : z == 1 ? Wk : Wo;
        unsigned short* dst = z == 0 ? Wqt : z == 1 ? Wkt : Wot;
        const int c0 = blockIdx.x * 32, r0 = blockIdx.y * 32;
        const int tx = t & 31, ty = t >> 5;
        #pragma unroll
        for (int i = ty; i < 32; i += 8)
            tile[i][tx] = src[(long)(r0 + i) * 1024 + c0 + tx];
        __syncthreads();
        #pragma unroll
        for (int i = ty; i < 32; i += 8)
            dst[(long)(c0 + i) * 1024 + r0 + tx] = f2b(tile[tx][i]);
        return;
    }
    if (z == 3) {
        const int i = (blockIdx.y * 32 + blockIdx.x) * 256 + t;
        float4 v = ((const float4*)Wv)[i];
        union { unsigned short u[4]; unsigned long long ll; } p;
        p.u[0] = f2b(v.x); p.u[1] = f2b(v.y); p.u[2] = f2b(v.z); p.u[3] = f2b(v.w);
        ((unsigned long long*)Wvb)[i] = p.ll;
        return;
    }
    if (z < 6) {
        const int bl = (z - 4) * 1024 + blockIdx.y * 32 + blockIdx.x;
        #pragma unroll
        for (int k = 0; k < 4; k++) {
            const int i = bl * 1024 + k * 256 + t;
            float4 v = ((const float4*)x)[i];
            union { unsigned short u[4]; unsigned long long ll; } p;
            p.u[0] = f2b(v.x); p.u[1] = f2b(v.y); p.u[2] = f2b(v.z); p.u[3] = f2b(v.w);
            ((unsigned long long*)xb)[i] = p.ll;
        }
        return;
    }
    // z == 6: bvo. Only y==0 blocks work; block x handles n in [x*32, x*32+32).
    if (blockIdx.y != 0) return;
    const int tx = t & 31, ty = t >> 5;
    const int n = blockIdx.x * 32 + tx;
    float acc = 0.f;
    #pragma unroll 4
    for (int j = 0; j < 128; j++) {
        const int k = ty * 128 + j;
        acc += Wo[(long)k * 1024 + n] * bv[k];
    }
    float* red = &tile[0][0];  // reuse: 8x32 floats
    red[ty * 32 + tx] = acc;
    __syncthreads();
    if (ty == 0) {
        float s = 0.f;
        #pragma unroll
        for (int j = 0; j < 8; j++) s += red[j * 32 + tx];
        bvo[n] = s + bo[n];
    }
}

// ---- 128-tile K-loop body (gemm128: Wvo prep only) ----
#define TILE_KLOOP(As, Bs, gA, lda, gB, ldb, Keff) \
    for (int k0 = 0; k0 < (Keff); k0 += 64) { \
        _Pragma("unroll") for (int p = 0; p < 2; p++) \
            _Pragma("unroll") for (int h = 0; h < 2; h++) { \
                gl_lds16((gA) + (long)h * 16 * (lda) + k0 + p * 32, \
                         &(As)[p * 4096 + (w * 32 + h * 16) * 32]); \
                gl_lds16((gB) + (long)h * 16 * (ldb) + k0 + p * 32, \
                         &(Bs)[p * 4096 + (w * 32 + h * 16) * 32]); \
            } \
        __syncthreads(); \
        _Pragma("unroll") for (int p = 0; p < 2; p++) { \
            short8 af[4], bfr[4]; \
            _Pragma("unroll") for (int mi = 0; mi < 4; mi++) \
                af[mi] = *(const short8*)&(As)[p * 4096 + (wr * 64 + mi * 16 + lrow) * 32 + quad * 8]; \
            _Pragma("unroll") for (int ni = 0; ni < 4; ni++) \
                bfr[ni] = *(const short8*)&(Bs)[p * 4096 + (wc * 64 + ni * 16 + lrow) * 32 + quad * 8]; \
            _Pragma("unroll") for (int mi = 0; mi < 4; mi++) \
                _Pragma("unroll") for (int ni = 0; ni < 4; ni++) \
                    acc[mi][ni] = __builtin_amdgcn_mfma_f32_16x16x32_bf16( \
                        af[mi], bfr[ni], acc[mi][ni], 0, 0, 0); \
        } \
        __syncthreads(); \
    }

#define TILE_DECLS \
    const int t = threadIdx.x, lane = t & 63, w = t >> 6; \
    const int wr = w >> 1, wc = w & 1; \
    const int lrow = lane & 15, quad = lane >> 4; \
    f32x4 acc[4][4]; \
    _Pragma("unroll") for (int i = 0; i < 4; i++) \
        _Pragma("unroll") for (int j = 0; j < 4; j++) \
            acc[i][j] = (f32x4){0.f, 0.f, 0.f, 0.f};

__global__ __launch_bounds__(256) void gemm128(
    const unsigned short* __restrict__ A, const unsigned short* __restrict__ Bt,
    unsigned short* __restrict__ C)
{
    __shared__ __attribute__((aligned(16))) unsigned short As[2 * 128 * 32];
    __shared__ __attribute__((aligned(16))) unsigned short Bs[2 * 128 * 32];
    const int m0 = blockIdx.x * 128, n0 = blockIdx.y * 128;

    TILE_DECLS

    const unsigned short* gA = A  + (long)(m0 + w * 32 + (lane >> 2)) * 1024 + (lane & 3) * 8;
    const unsigned short* gB = Bt + (long)(n0 + w * 32 + (lane >> 2)) * 1024 + (lane & 3) * 8;
    TILE_KLOOP(As, Bs, gA, 1024, gB, 1024, 1024)

    #pragma unroll
    for (int mi = 0; mi < 4; mi++) {
        const int m = m0 + wr * 64 + mi * 16 + quad * 4;
        #pragma unroll
        for (int ni = 0; ni < 4; ni++) {
            const int n = n0 + wc * 64 + ni * 16 + lrow;
            #pragma unroll
            for (int rg = 0; rg < 4; rg++)
                C[(long)(m + rg) * 1024 + n] = f2b(acc[mi][ni][rg]);
        }
    }
}

// ---- shared 2-B-panel machinery (QK2) ----
#define TILE2_DECLS \
    const int t = threadIdx.x, lane = t & 63, w = t >> 6; \
    const int wr = w >> 1, wc = w & 1; \
    const int lrow = lane & 15, quad = lane >> 4; \
    f32x4 acc0[4][4], acc1[4][4]; \
    _Pragma("unroll") for (int i = 0; i < 4; i++) \
        _Pragma("unroll") for (int j = 0; j < 4; j++) { \
            acc0[i][j] = (f32x4){0.f, 0.f, 0.f, 0.f}; \
            acc1[i][j] = (f32x4){0.f, 0.f, 0.f, 0.f}; \
        }

#define TILE2_KLOOP(gA, lda, gB0, gB1, ldb, Keff) \
    for (int k0 = 0; k0 < (Keff); k0 += 64) { \
        _Pragma("unroll") for (int p = 0; p < 2; p++) \
            _Pragma("unroll") for (int h = 0; h < 2; h++) { \
                const int ldst = p * 4096 + (w * 32 + h * 16) * 32; \
                const long gofs = (long)h * 16 * (lda) + k0 + p * 32; \
                const long gofsB = (long)h * 16 * (ldb) + k0 + p * 32; \
                gl_lds16((gA)  + gofs,  &As[ldst]); \
                gl_lds16((gB0) + gofsB, &Bs0[ldst]); \
                gl_lds16((gB1) + gofsB, &Bs1[ldst]); \
            } \
        __syncthreads(); \
        _Pragma("unroll") for (int p = 0; p < 2; p++) { \
            short8 af[4], bfr[4]; \
            _Pragma("unroll") for (int mi = 0; mi < 4; mi++) \
                af[mi] = *(const short8*)&As[p * 4096 + (wr * 64 + mi * 16 + lrow) * 32 + quad * 8]; \
            _Pragma("unroll") for (int ni = 0; ni < 4; ni++) \
                bfr[ni] = *(const short8*)&Bs0[p * 4096 + (wc * 64 + ni * 16 + lrow) * 32 + quad * 8]; \
            _Pragma("unroll") for (int mi = 0; mi < 4; mi++) \
                _Pragma("unroll") for (int ni = 0; ni < 4; ni++) \
                    acc0[mi][ni] = __builtin_amdgcn_mfma_f32_16x16x32_bf16( \
                        af[mi], bfr[ni], acc0[mi][ni], 0, 0, 0); \
            _Pragma("unroll") for (int ni = 0; ni < 4; ni++) \
                bfr[ni] = *(const short8*)&Bs1[p * 4096 + (wc * 64 + ni * 16 + lrow) * 32 + quad * 8]; \
            _Pragma("unroll") for (int mi = 0; mi < 4; mi++) \
                _Pragma("unroll") for (int ni = 0; ni < 4; ni++) \
                    acc1[mi][ni] = __builtin_amdgcn_mfma_f32_16x16x32_bf16( \
                        af[mi], bfr[ni], acc1[mi][ni], 0, 0, 0); \
        } \
        __syncthreads(); \
    }

// QK^T with triangular PAIR grid: 72 pairs/batch; pair bp covers bn={2bp,2bp+1}.
// Overflow tile (bn=bm+1, even bm) is strictly above the diagonal: written
// unconditionally, never read by softmax (padded<=...) nor PV (Keff cap).
__global__ __launch_bounds__(256, 2) void gemm_qk2(
    const unsigned short* __restrict__ Q, const unsigned short* __restrict__ Km,
    unsigned short* __restrict__ S)
{
    __shared__ __attribute__((aligned(16))) unsigned short As[8192];
    __shared__ __attribute__((aligned(16))) unsigned short Bs0[8192];
    __shared__ __attribute__((aligned(16))) unsigned short Bs1[8192];

    const int q = 71 - blockIdx.x;  // heavy-first
    int tq = (int)sqrtf((float)q);
    while (tq * tq + tq > q) tq--;
    while ((tq + 1) * (tq + 1) + (tq + 1) <= q) tq++;
    int bm, bp;
    if (q >= (tq + 1) * (tq + 1)) { bm = 2 * tq + 1; bp = q - (tq + 1) * (tq + 1); }
    else                          { bm = 2 * tq;     bp = q - (tq * tq + tq); }
    const int bz = blockIdx.y;
    const unsigned short* A  = Q  + (long)bz * 2048 * 1024;
    const unsigned short* Bt = Km + (long)bz * 2048 * 1024;
    const int m0 = bm * 128, n0 = bp * 256;

    TILE2_DECLS

    const unsigned short* gA  = A  + (long)(m0 + w * 32 + (lane >> 2)) * 1024 + (lane & 3) * 8;
    const unsigned short* gB0 = Bt + (long)(n0 + w * 32 + (lane >> 2)) * 1024 + (lane & 3) * 8;
    const unsigned short* gB1 = gB0 + 128L * 1024;
    TILE2_KLOOP(gA, 1024, gB0, gB1, 1024, 1024)

    unsigned short* Sb = S + (long)bz * 2048 * 2048;
    #pragma unroll
    for (int mi = 0; mi < 4; mi++) {
        const int m = m0 + wr * 64 + mi * 16 + quad * 4;
        #pragma unroll
        for (int ni = 0; ni < 4; ni++) {
            const int nl = wc * 64 + ni * 16 + lrow;
            #pragma unroll
            for (int rg = 0; rg < 4; rg++) {
                Sb[(long)(m + rg) * 2048 + n0 + nl]       = f2b(acc0[mi][ni][rg] * 0.03125f);
                Sb[(long)(m + rg) * 2048 + n0 + 128 + nl] = f2b(acc1[mi][ni][rg] * 0.03125f);
            }
        }
    }
}

// PV, depth-optimized: 128x64 tiles, grid (16 bn fastest, 16 bm heavy-first, 4 bz)
// = 1024 blocks, 24 KB LDS, 4 blocks/CU -> co-resident blocks hide the per-iter
// stage/drain latency (the r5 6-deep datapoint: 0.75 vs 1.9 us/iter at 1-2/CU).
// bn-fastest: 16 consecutive blocks co-read one S panel (L2/L3 broadcast).
__global__ __launch_bounds__(256, 4) void gemm_pv1(
    const unsigned short* __restrict__ S, const unsigned short* __restrict__ Vot,
    const float* __restrict__ bvo, float* __restrict__ out)
{
    __shared__ __attribute__((aligned(16))) unsigned short As[8192];  // 128x64 bf16
    __shared__ __attribute__((aligned(16))) unsigned short Bs[4096];  //  64x64 bf16

    const int bn = blockIdx.x;            // 0..15
    const int bm = 15 - (int)blockIdx.y;  // heavy-first
    const int bz = blockIdx.z;
    const unsigned short* A  = S   + (long)bz * 2048 * 2048;
    const unsigned short* Bt = Vot + (long)bz * 2048;
    const int m0 = bm * 128, n0 = bn * 64;
    const int Keff = (bm + 1) * 128;

    const int t = threadIdx.x, lane = t & 63, w = t >> 6;
    const int lrow = lane & 15, quad = lane >> 4;

    f32x4 acc[2][4];
    #pragma unroll
    for (int i = 0; i < 2; i++)
        #pragma unroll
        for (int j = 0; j < 4; j++)
            acc[i][j] = (f32x4){0.f, 0.f, 0.f, 0.f};

    const unsigned short* gA = A  + (long)(m0 + w * 32 + (lane >> 2)) * 2048 + (lane & 3) * 8;
    const unsigned short* gB = Bt + (long)(n0 + w * 16 + (lane >> 2)) * 8192 + (lane & 3) * 8;

    for (int k0 = 0; k0 < Keff; k0 += 64) {
        #pragma unroll
        for (int p = 0; p < 2; p++) {
            #pragma unroll
            for (int h = 0; h < 2; h++)
                gl_lds16(gA + (long)h * 16 * 2048 + k0 + p * 32,
                         &As[p * 4096 + (w * 32 + h * 16) * 32]);
            gl_lds16(gB + k0 + p * 32, &Bs[p * 2048 + (w * 16) * 32]);
        }
        __syncthreads();
        #pragma unroll
        for (int p = 0; p < 2; p++) {
            short8 af[2], bfr[4];
            #pragma unroll
            for (int mi = 0; mi < 2; mi++)
                af[mi] = *(const short8*)&As[p * 4096 + (w * 32 + mi * 16 + lrow) * 32 + quad * 8];
            #pragma unroll
            for (int ni = 0; ni < 4; ni++)
                bfr[ni] = *(const short8*)&Bs[p * 2048 + (ni * 16 + lrow) * 32 + quad * 8];
            #pragma unroll
            for (int mi = 0; mi < 2; mi++)
                #pragma unroll
                for (int ni = 0; ni < 4; ni++)
                    acc[mi][ni] = __builtin_amdgcn_mfma_f32_16x16x32_bf16(
                        af[mi], bfr[ni], acc[mi][ni], 0, 0, 0);
        }
        __syncthreads();
    }

    float* ob = out + (long)bz * 2048 * 1024;
    #pragma unroll
    for (int mi = 0; mi < 2; mi++) {
        const int m = m0 + w * 32 + mi * 16 + quad * 4;
        #pragma unroll
        for (int ni = 0; ni < 4; ni++) {
            const int n = n0 + ni * 16 + lrow;
            const float bvl = bvo[n];
            #pragma unroll
            for (int rg = 0; rg < 4; rg++)
                ob[(long)(m + rg) * 1024 + n] = acc[mi][ni][rg] + bvl;
        }
    }
}

// Fused QKV projection, r-FUSED: A-tile staged once per K-step for 3 B-panels.
__global__ __launch_bounds__(256, 2) void qkv_proj(
    const unsigned short* __restrict__ A,
    const unsigned short* __restrict__ Wqt, const unsigned short* __restrict__ Wkt,
    const unsigned short* __restrict__ Wvot,
    const float* __restrict__ bq, const float* __restrict__ bk,
    unsigned short* __restrict__ Q, unsigned short* __restrict__ Km,
    unsigned short* __restrict__ Vot)
{
    __shared__ __attribute__((aligned(16))) unsigned short smem[32768];  // 64 KiB
    unsigned short* As  = smem;
    unsigned short* Bs0 = smem + 8192;
    unsigned short* Bs1 = smem + 16384;
    unsigned short* Bs2 = smem + 24576;
    unsigned short* pool = smem;  // epilogue alias (32 KiB)

    const int bid = blockIdx.x;
    const int bnn = bid & 7, bm = bid >> 3;   // bnn-fastest: 8 consecutive blocks share A
    const int m0 = bm * 128, n0 = bnn * 128;

    const int t = threadIdx.x, lane = t & 63, w = t >> 6;
    const int wr = w >> 1, wc = w & 1;
    const int lrow = lane & 15, quad = lane >> 4;

    f32x4 accQ[4][4], accK[4][4], accV[4][4];
    #pragma unroll
    for (int i = 0; i < 4; i++)
        #pragma unroll
        for (int j = 0; j < 4; j++) {
            accQ[i][j] = (f32x4){0.f, 0.f, 0.f, 0.f};
            accK[i][j] = (f32x4){0.f, 0.f, 0.f, 0.f};
            accV[i][j] = (f32x4){0.f, 0.f, 0.f, 0.f};
        }

    const long rowA = (long)(m0 + w * 32 + (lane >> 2)) * 1024 + (lane & 3) * 8;
    const long rowB = (long)(n0 + w * 32 + (lane >> 2)) * 1024 + (lane & 3) * 8;
    const unsigned short* gA  = A    + rowA;
    const unsigned short* gB0 = Wqt  + rowB;
    const unsigned short* gB1 = Wkt  + rowB;
    const unsigned short* gB2 = Wvot + rowB;

    for (int k0 = 0; k0 < 1024; k0 += 64) {
        #pragma unroll
        for (int p = 0; p < 2; p++)
            #pragma unroll
            for (int h = 0; h < 2; h++) {
                const int ldst = p * 4096 + (w * 32 + h * 16) * 32;
                const long gofs = (long)h * 16 * 1024 + k0 + p * 32;
                gl_lds16(gA  + gofs, &As[ldst]);
                gl_lds16(gB0 + gofs, &Bs0[ldst]);
                gl_lds16(gB1 + gofs, &Bs1[ldst]);
                gl_lds16(gB2 + gofs, &Bs2[ldst]);
            }
        __syncthreads();
        #pragma unroll
        for (int p = 0; p < 2; p++) {
            short8 af[4], bfr[4];
            #pragma unroll
            for (int mi = 0; mi < 4; mi++)
                af[mi] = *(const short8*)&As[p * 4096 + (wr * 64 + mi * 16 + lrow) * 32 + quad * 8];
            #pragma unroll
            for (int ni = 0; ni < 4; ni++)
                bfr[ni] = *(const short8*)&Bs0[p * 4096 + (wc * 64 + ni * 16 + lrow) * 32 + quad * 8];
            #pragma unroll
            for (int mi = 0; mi < 4; mi++)
                #pragma unroll
                for (int ni = 0; ni < 4; ni++)
                    accQ[mi][ni] = __builtin_amdgcn_mfma_f32_16x16x32_bf16(
                        af[mi], bfr[ni], accQ[mi][ni], 0, 0, 0);
            #pragma unroll
            for (int ni = 0; ni < 4; ni++)
                bfr[ni] = *(const short8*)&Bs1[p * 4096 + (wc * 64 + ni * 16 + lrow) * 32 + quad * 8];
            #pragma unroll
            for (int mi = 0; mi < 4; mi++)
                #pragma unroll
                for (int ni = 0; ni < 4; ni++)
                    accK[mi][ni] = __builtin_amdgcn_mfma_f32_16x16x32_bf16(
                        af[mi], bfr[ni], accK[mi][ni], 0, 0, 0);
            #pragma unroll
            for (int ni = 0; ni < 4; ni++)
                bfr[ni] = *(const short8*)&Bs2[p * 4096 + (wc * 64 + ni * 16 + lrow) * 32 + quad * 8];
            #pragma unroll
            for (int mi = 0; mi < 4; mi++)
                #pragma unroll
                for (int ni = 0; ni < 4; ni++)
                    accV[mi][ni] = __builtin_amdgcn_mfma_f32_16x16x32_bf16(
                        af[mi], bfr[ni], accV[mi][ni], 0, 0, 0);
        }
        __syncthreads();
    }

    // --- Q epilogue (coalesced via pool) ---
    #pragma unroll
    for (int mi = 0; mi < 4; mi++)
        #pragma unroll
        for (int ni = 0; ni < 4; ni++) {
            const int n_l = wc * 64 + ni * 16 + lrow;
            const float bvl = bq[n0 + n_l];
            #pragma unroll
            for (int rg = 0; rg < 4; rg++) {
                const int m_l = wr * 64 + mi * 16 + quad * 4 + rg;
                pool[m_l * 128 + n_l] = f2b(accQ[mi][ni][rg] + bvl);
            }
        }
    __syncthreads();
    #pragma unroll
    for (int it = 0; it < 8; it++) {
        const int idx = it * 256 + t;
        const int m_l = idx >> 4, c = idx & 15;
        short8 v = *(const short8*)&pool[m_l * 128 + c * 8];
        *(short8*)&Q[(long)(m0 + m_l) * 1024 + n0 + c * 8] = v;
    }
    __syncthreads();

    // --- K epilogue ---
    #pragma unroll
    for (int mi = 0; mi < 4; mi++)
        #pragma unroll
        for (int ni = 0; ni < 4; ni++) {
            const int n_l = wc * 64 + ni * 16 + lrow;
            const float bvl = bk[n0 + n_l];
            #pragma unroll
            for (int rg = 0; rg < 4; rg++) {
                const int m_l = wr * 64 + mi * 16 + quad * 4 + rg;
                pool[m_l * 128 + n_l] = f2b(accK[mi][ni][rg] + bvl);
            }
        }
    __syncthreads();
    #pragma unroll
    for (int it = 0; it < 8; it++) {
        const int idx = it * 256 + t;
        const int m_l = idx >> 4, c = idx & 15;
        short8 v = *(const short8*)&pool[m_l * 128 + c * 8];
        *(short8*)&Km[(long)(m0 + m_l) * 1024 + n0 + c * 8] = v;
    }
    __syncthreads();

    // --- Vot epilogue (transposed, XOR-swizzled pool) ---
    #pragma unroll
    for (int mi = 0; mi < 4; mi++)
        #pragma unroll
        for (int ni = 0; ni < 4; ni++) {
            const int n_l = wc * 64 + ni * 16 + lrow;
            const int mb = wr * 64 + mi * 16 + quad * 4;
            union { unsigned short u[4]; unsigned long long ll; } pk;
            #pragma unroll
            for (int rg = 0; rg < 4; rg++) pk.u[rg] = f2b(accV[mi][ni][rg]);
            *(unsigned long long*)&pool[n_l * 128 + (mb ^ ((n_l & 15) << 3))] = pk.ll;
        }
    __syncthreads();
    #pragma unroll
    for (int it = 0; it < 8; it++) {
        const int idx = it * 256 + t;
        const int n_l = idx >> 4, c = idx & 15;
        short8 v = *(const short8*)&pool[n_l * 128 + ((c * 8) ^ ((n_l & 15) << 3))];
        *(short8*)&Vot[(long)(n0 + n_l) * 8192 + m0 + c * 8] = v;
    }
}

// Single-pass causal row softmax, 128-granular padding (PV uses 128-tile K cap).
__global__ __launch_bounds__(256) void softmax_causal(unsigned short* __restrict__ S)
{
    const int i = blockIdx.x;
    const int t = threadIdx.x;
    const int padded = ((i >> 7) + 1) << 7;
    const int j0 = t * 8;
    const bool active = j0 < padded;

    __shared__ float red[4];

    for (int b = 0; b < 4; b++) {
        unsigned short* base = S + ((long)b * 2048 + i) * 2048;

        float v[8];
        if (active) {
            short8 s8 = *(const short8*)(base + j0);
            #pragma unroll
            for (int jj = 0; jj < 8; jj++)
                v[jj] = (j0 + jj <= i) ? b2f((unsigned short)s8[jj]) : -3.0e38f;
        } else {
            #pragma unroll
            for (int jj = 0; jj < 8; jj++) v[jj] = -3.0e38f;
        }

        float lmax = v[0];
        #pragma unroll
        for (int jj = 1; jj < 8; jj++) lmax = fmaxf(lmax, v[jj]);
        #pragma unroll
        for (int off = 32; off > 0; off >>= 1) lmax = fmaxf(lmax, __shfl_xor(lmax, off, 64));
        if ((t & 63) == 0) red[t >> 6] = lmax;
        __syncthreads();
        const float gmax = fmaxf(fmaxf(red[0], red[1]), fmaxf(red[2], red[3]));
        __syncthreads();

        float lsum = 0.f;
        #pragma unroll
        for (int jj = 0; jj < 8; jj++) {
            v[jj] = (v[jj] > -1.0e37f) ? __expf(v[jj] - gmax) : 0.f;
            lsum += v[jj];
        }
        #pragma unroll
        for (int off = 32; off > 0; off >>= 1) lsum += __shfl_xor(lsum, off, 64);
        if ((t & 63) == 0) red[t >> 6] = lsum;
        __syncthreads();
        const float inv = 1.0f / (red[0] + red[1] + red[2] + red[3]);

        if (active) {
            short8 p8;
            #pragma unroll
            for (int jj = 0; jj < 8; jj++) p8[jj] = (short)f2b(v[jj] * inv);
            *(short8*)(base + j0) = p8;
        }
        __syncthreads();  // red[] reused next batch
    }
}

extern "C" void kernel_launch(void* const* d_in, const int* in_sizes, int n_in,
                              void* d_out, int out_size, void* d_ws, size_t ws_size,
                              hipStream_t stream)
{
    const float* x  = (const float*)d_in[0];
    const float* Wq = (const float*)d_in[2];
    const float* bq = (const float*)d_in[3];
    const float* Wk = (const float*)d_in[4];
    const float* bk = (const float*)d_in[5];
    const float* Wv = (const float*)d_in[6];
    const float* bv = (const float*)d_in[7];
    const float* Wo = (const float*)d_in[8];
    const float* bo = (const float*)d_in[9];

    unsigned short* ws = (unsigned short*)d_ws;
    const long XSZ = 8192L * 1024;
    const long WSZ = 1024L * 1024;
    unsigned short* xb   = ws;                // [8192,1024] bf16
    unsigned short* Wqt  = ws + XSZ;          // Wq^T bf16
    unsigned short* Wkt  = Wqt + WSZ;         // Wk^T bf16
    unsigned short* Wot  = Wkt + WSZ;         // Wo^T bf16
    unsigned short* Wvb  = Wot + WSZ;         // Wv bf16 (plain)
    unsigned short* Wvot = Wvb + WSZ;         // (Wv@Wo)^T bf16
    unsigned short* Q    = Wvot + WSZ;        // [8192,1024]
    unsigned short* Km   = Q + XSZ;           // [8192,1024]
    unsigned short* Vot  = Km + XSZ;          // [1024,8192] = (x@Wvo)^T
    unsigned short* S    = Vot + XSZ;         // [4][2048,2048] (S -> P in place)
    float*          bvo  = (float*)(S + 4L * 2048 * 2048);   // [1024] fp32

    const dim3 blk(256);

    // merged prep: weights + x convert + bvo, one dispatch
    prep<<<dim3(32, 32, 7), blk, 0, stream>>>(
        x, Wq, Wk, Wo, Wv, bv, bo, xb, Wqt, Wkt, Wot, Wvb, bvo);

    // Wvo^T = Wo^T @ Wv^T
    gemm128<<<dim3(8, 8), blk, 0, stream>>>(Wot, Wvb, Wvot);

    // fused QKV projection (r-fused: A staged once for 3 B-panels)
    qkv_proj<<<dim3(512), blk, 0, stream>>>(
        xb, Wqt, Wkt, Wvot, bq, bk, Q, Km, Vot);

    // S = Q K^T / sqrt(D), triangular pair grid (2 bn tiles per block)
    gemm_qk2<<<dim3(72, 4), blk, 0, stream>>>(Q, Km, S);

    softmax_causal<<<dim3(2048), blk, 0, stream>>>(S);

    // out = P @ Vo + bvo, 128x64 tiles, 1024 blocks @ 4/CU, heavy-first
    gemm_pv1<<<dim3(16, 16, 4), blk, 0, stream>>>(S, Vot, bvo, (float*)d_out);
}

// Round 9
// 302.890 us; speedup vs baseline: 1.1347x; 1.0783x over previous
//
#include <hip/hip_runtime.h>
#include <hip/hip_bf16.h>

typedef __attribute__((ext_vector_type(8))) short short8;
typedef __attribute__((ext_vector_type(4))) float f32x4;

__device__ inline float b2f(unsigned short u) {
    union { unsigned int i; float f; } c; c.i = ((unsigned int)u) << 16; return c.f;
}
__device__ inline unsigned short f2b(float f) {
    __hip_bfloat16 h = __float2bfloat16(f);
    return *reinterpret_cast<unsigned short*>(&h);
}

// async global->LDS, 16 B per lane; LDS dest = wave-uniform base + lane*16
__device__ inline void gl_lds16(const unsigned short* g, unsigned short* ldsbase) {
    __builtin_amdgcn_global_load_lds(
        (const __attribute__((address_space(1))) unsigned int*)(g),
        (__attribute__((address_space(3))) unsigned int*)(ldsbase),
        16, 0, 0);
}

// ---- merged prep: weights transpose/convert + x convert + bvo, ONE dispatch ----
__global__ __launch_bounds__(256) void prep(
    const float* __restrict__ x,
    const float* __restrict__ Wq, const float* __restrict__ Wk,
    const float* __restrict__ Wo, const float* __restrict__ Wv,
    const float* __restrict__ bv, const float* __restrict__ bo,
    unsigned short* __restrict__ xb,
    unsigned short* __restrict__ Wqt, unsigned short* __restrict__ Wkt,
    unsigned short* __restrict__ Wot, unsigned short* __restrict__ Wvb,
    float* __restrict__ bvo)
{
    const int z = blockIdx.z;
    const int t = threadIdx.x;
    __shared__ float tile[32][33];

    if (z < 3) {
        const float* src = z == 0 ? Wq : z == 1 ? Wk : Wo;
        unsigned short* dst = z == 0 ? Wqt : z == 1 ? Wkt : Wot;
        const int c0 = blockIdx.x * 32, r0 = blockIdx.y * 32;
        const int tx = t & 31, ty = t >> 5;
        #pragma unroll
        for (int i = ty; i < 32; i += 8)
            tile[i][tx] = src[(long)(r0 + i) * 1024 + c0 + tx];
        __syncthreads();
        #pragma unroll
        for (int i = ty; i < 32; i += 8)
            dst[(long)(c0 + i) * 1024 + r0 + tx] = f2b(tile[tx][i]);
        return;
    }
    if (z == 3) {
        const int i = (blockIdx.y * 32 + blockIdx.x) * 256 + t;
        float4 v = ((const float4*)Wv)[i];
        union { unsigned short u[4]; unsigned long long ll; } p;
        p.u[0] = f2b(v.x); p.u[1] = f2b(v.y); p.u[2] = f2b(v.z); p.u[3] = f2b(v.w);
        ((unsigned long long*)Wvb)[i] = p.ll;
        return;
    }
    if (z < 6) {
        const int bl = (z - 4) * 1024 + blockIdx.y * 32 + blockIdx.x;
        #pragma unroll
        for (int k = 0; k < 4; k++) {
            const int i = bl * 1024 + k * 256 + t;
            float4 v = ((const float4*)x)[i];
            union { unsigned short u[4]; unsigned long long ll; } p;
            p.u[0] = f2b(v.x); p.u[1] = f2b(v.y); p.u[2] = f2b(v.z); p.u[3] = f2b(v.w);
            ((unsigned long long*)xb)[i] = p.ll;
        }
        return;
    }
    // z == 6: bvo. Only y==0 blocks work; block x handles n in [x*32, x*32+32).
    if (blockIdx.y != 0) return;
    const int tx = t & 31, ty = t >> 5;
    const int n = blockIdx.x * 32 + tx;
    float acc = 0.f;
    #pragma unroll 4
    for (int j = 0; j < 128; j++) {
        const int k = ty * 128 + j;
        acc += Wo[(long)k * 1024 + n] * bv[k];
    }
    float* red = &tile[0][0];  // reuse: 8x32 floats
    red[ty * 32 + tx] = acc;
    __syncthreads();
    if (ty == 0) {
        float s = 0.f;
        #pragma unroll
        for (int j = 0; j < 8; j++) s += red[j * 32 + tx];
        bvo[n] = s + bo[n];
    }
}

// Wvo^T = Wot @ Wvb^T, BK=256 single-buffered (4 K-iters instead of 32):
// at 64 blocks = 1 block/CU there is no co-resident partner to hide the
// barrier drain, so minimize barrier count. 128 KB LDS. XOR chunk swizzle
// applied to the gl_lds SOURCE (LDS dest linear, rule both-sides-or-neither)
// and to the ds_read address.
__global__ __launch_bounds__(256, 1) void gemm_wvo(
    const unsigned short* __restrict__ Wot, const unsigned short* __restrict__ Wvb,
    unsigned short* __restrict__ Wvot)
{
    __shared__ __attribute__((aligned(16))) unsigned short As[128 * 256];  // 64 KB
    __shared__ __attribute__((aligned(16))) unsigned short Bs[128 * 256];  // 64 KB
    const int m0 = blockIdx.x * 128, n0 = blockIdx.y * 128;
    const int t = threadIdx.x, lane = t & 63, w = t >> 6;
    const int wr = w >> 1, wc = w & 1;
    const int lrow = lane & 15, quad = lane >> 4;

    f32x4 acc[4][4];
    #pragma unroll
    for (int i = 0; i < 4; i++)
        #pragma unroll
        for (int j = 0; j < 4; j++)
            acc[i][j] = (f32x4){0.f, 0.f, 0.f, 0.f};

    for (int k0 = 0; k0 < 1024; k0 += 256) {
        // stage 128x256 of A and B: 4096 16-B chunks each, 16 per thread.
        // chunk id -> row = id>>5, slot = id&31; source chunk = slot ^ (row&7).
        #pragma unroll
        for (int c = 0; c < 16; c++) {
            const int id = c * 256 + t;
            const int row = id >> 5;
            const int src = (id & 31) ^ (row & 7);
            gl_lds16(Wot + (long)(m0 + row) * 1024 + k0 + src * 8,
                     &As[(c * 256 + w * 64) * 8]);
            gl_lds16(Wvb + (long)(n0 + row) * 1024 + k0 + src * 8,
                     &Bs[(c * 256 + w * 64) * 8]);
        }
        __syncthreads();
        #pragma unroll
        for (int kp = 0; kp < 8; kp++) {
            short8 af[4], bfr[4];
            #pragma unroll
            for (int mi = 0; mi < 4; mi++) {
                const int r = wr * 64 + mi * 16 + lrow;
                af[mi] = *(const short8*)&As[r * 256 + (((kp * 4 + quad) ^ (r & 7)) << 3)];
            }
            #pragma unroll
            for (int ni = 0; ni < 4; ni++) {
                const int r = wc * 64 + ni * 16 + lrow;
                bfr[ni] = *(const short8*)&Bs[r * 256 + (((kp * 4 + quad) ^ (r & 7)) << 3)];
            }
            #pragma unroll
            for (int mi = 0; mi < 4; mi++)
                #pragma unroll
                for (int ni = 0; ni < 4; ni++)
                    acc[mi][ni] = __builtin_amdgcn_mfma_f32_16x16x32_bf16(
                        af[mi], bfr[ni], acc[mi][ni], 0, 0, 0);
        }
        __syncthreads();
    }

    #pragma unroll
    for (int mi = 0; mi < 4; mi++) {
        const int m = m0 + wr * 64 + mi * 16 + quad * 4;
        #pragma unroll
        for (int ni = 0; ni < 4; ni++) {
            const int n = n0 + wc * 64 + ni * 16 + lrow;
            #pragma unroll
            for (int rg = 0; rg < 4; rg++)
                Wvot[(long)(m + rg) * 1024 + n] = f2b(acc[mi][ni][rg]);
        }
    }
}

// ---- shared 2-B-panel machinery (QK2) ----
#define TILE2_DECLS \
    const int t = threadIdx.x, lane = t & 63, w = t >> 6; \
    const int wr = w >> 1, wc = w & 1; \
    const int lrow = lane & 15, quad = lane >> 4; \
    f32x4 acc0[4][4], acc1[4][4]; \
    _Pragma("unroll") for (int i = 0; i < 4; i++) \
        _Pragma("unroll") for (int j = 0; j < 4; j++) { \
            acc0[i][j] = (f32x4){0.f, 0.f, 0.f, 0.f}; \
            acc1[i][j] = (f32x4){0.f, 0.f, 0.f, 0.f}; \
        }

#define TILE2_KLOOP(gA, lda, gB0, gB1, ldb, Keff) \
    for (int k0 = 0; k0 < (Keff); k0 += 64) { \
        _Pragma("unroll") for (int p = 0; p < 2; p++) \
            _Pragma("unroll") for (int h = 0; h < 2; h++) { \
                const int ldst = p * 4096 + (w * 32 + h * 16) * 32; \
                const long gofs = (long)h * 16 * (lda) + k0 + p * 32; \
                const long gofsB = (long)h * 16 * (ldb) + k0 + p * 32; \
                gl_lds16((gA)  + gofs,  &As[ldst]); \
                gl_lds16((gB0) + gofsB, &Bs0[ldst]); \
                gl_lds16((gB1) + gofsB, &Bs1[ldst]); \
            } \
        __syncthreads(); \
        _Pragma("unroll") for (int p = 0; p < 2; p++) { \
            short8 af[4], bfr[4]; \
            _Pragma("unroll") for (int mi = 0; mi < 4; mi++) \
                af[mi] = *(const short8*)&As[p * 4096 + (wr * 64 + mi * 16 + lrow) * 32 + quad * 8]; \
            _Pragma("unroll") for (int ni = 0; ni < 4; ni++) \
                bfr[ni] = *(const short8*)&Bs0[p * 4096 + (wc * 64 + ni * 16 + lrow) * 32 + quad * 8]; \
            _Pragma("unroll") for (int mi = 0; mi < 4; mi++) \
                _Pragma("unroll") for (int ni = 0; ni < 4; ni++) \
                    acc0[mi][ni] = __builtin_amdgcn_mfma_f32_16x16x32_bf16( \
                        af[mi], bfr[ni], acc0[mi][ni], 0, 0, 0); \
            _Pragma("unroll") for (int ni = 0; ni < 4; ni++) \
                bfr[ni] = *(const short8*)&Bs1[p * 4096 + (wc * 64 + ni * 16 + lrow) * 32 + quad * 8]; \
            _Pragma("unroll") for (int mi = 0; mi < 4; mi++) \
                _Pragma("unroll") for (int ni = 0; ni < 4; ni++) \
                    acc1[mi][ni] = __builtin_amdgcn_mfma_f32_16x16x32_bf16( \
                        af[mi], bfr[ni], acc1[mi][ni], 0, 0, 0); \
        } \
        __syncthreads(); \
    }

// QK^T with triangular PAIR grid: 72 pairs/batch; pair bp covers bn={2bp,2bp+1}.
// Overflow tile (bn=bm+1, even bm) is strictly above the diagonal: written
// unconditionally, never read by softmax (padded<=...) nor PV (Keff cap).
__global__ __launch_bounds__(256, 2) void gemm_qk2(
    const unsigned short* __restrict__ Q, const unsigned short* __restrict__ Km,
    unsigned short* __restrict__ S)
{
    __shared__ __attribute__((aligned(16))) unsigned short As[8192];
    __shared__ __attribute__((aligned(16))) unsigned short Bs0[8192];
    __shared__ __attribute__((aligned(16))) unsigned short Bs1[8192];

    const int q = 71 - blockIdx.x;  // heavy-first
    int tq = (int)sqrtf((float)q);
    while (tq * tq + tq > q) tq--;
    while ((tq + 1) * (tq + 1) + (tq + 1) <= q) tq++;
    int bm, bp;
    if (q >= (tq + 1) * (tq + 1)) { bm = 2 * tq + 1; bp = q - (tq + 1) * (tq + 1); }
    else                          { bm = 2 * tq;     bp = q - (tq * tq + tq); }
    const int bz = blockIdx.y;
    const unsigned short* A  = Q  + (long)bz * 2048 * 1024;
    const unsigned short* Bt = Km + (long)bz * 2048 * 1024;
    const int m0 = bm * 128, n0 = bp * 256;

    TILE2_DECLS

    const unsigned short* gA  = A  + (long)(m0 + w * 32 + (lane >> 2)) * 1024 + (lane & 3) * 8;
    const unsigned short* gB0 = Bt + (long)(n0 + w * 32 + (lane >> 2)) * 1024 + (lane & 3) * 8;
    const unsigned short* gB1 = gB0 + 128L * 1024;
    TILE2_KLOOP(gA, 1024, gB0, gB1, 1024, 1024)

    unsigned short* Sb = S + (long)bz * 2048 * 2048;
    #pragma unroll
    for (int mi = 0; mi < 4; mi++) {
        const int m = m0 + wr * 64 + mi * 16 + quad * 4;
        #pragma unroll
        for (int ni = 0; ni < 4; ni++) {
            const int nl = wc * 64 + ni * 16 + lrow;
            #pragma unroll
            for (int rg = 0; rg < 4; rg++) {
                Sb[(long)(m + rg) * 2048 + n0 + nl]       = f2b(acc0[mi][ni][rg] * 0.03125f);
                Sb[(long)(m + rg) * 2048 + n0 + 128 + nl] = f2b(acc1[mi][ni][rg] * 0.03125f);
            }
        }
    }
}

// PV: 128x64 tiles, 1024 blocks, 5 blocks/CU capacity. XCD-chunked bijective
// mapping (T1): xcd = bid&7 owns 8 balanced (bm,bz) S-panels (rank = j*8+xcd
// spreads heavy/light evenly) and sweeps all 16 bn tiles per panel -> each
// S panel is fetched into one XCD's L2 once and reused 16x.
__global__ __launch_bounds__(256, 5) void gemm_pv1(
    const unsigned short* __restrict__ S, const unsigned short* __restrict__ Vot,
    const float* __restrict__ bvo, float* __restrict__ out)
{
    __shared__ __attribute__((aligned(16))) unsigned short As[8192];  // 128x64 bf16
    __shared__ __attribute__((aligned(16))) unsigned short Bs[4096];  //  64x64 bf16

    const int bid = blockIdx.x;
    const int xcd = bid & 7, s = bid >> 3;
    const int bn = s & 15, j = s >> 4;          // bn fastest within the XCD chunk
    const int rank = j * 8 + xcd;               // 0..63, heavy-first in dispatch order
    const int bz = rank & 3;
    const int bm = 15 - (rank >> 2);
    const unsigned short* A  = S   + (long)bz * 2048 * 2048;
    const unsigned short* Bt = Vot + (long)bz * 2048;
    const int m0 = bm * 128, n0 = bn * 64;
    const int Keff = (bm + 1) * 128;

    const int t = threadIdx.x, lane = t & 63, w = t >> 6;
    const int lrow = lane & 15, quad = lane >> 4;

    f32x4 acc[2][4];
    #pragma unroll
    for (int i = 0; i < 2; i++)
        #pragma unroll
        for (int jj = 0; jj < 4; jj++)
            acc[i][jj] = (f32x4){0.f, 0.f, 0.f, 0.f};

    const unsigned short* gA = A  + (long)(m0 + w * 32 + (lane >> 2)) * 2048 + (lane & 3) * 8;
    const unsigned short* gB = Bt + (long)(n0 + w * 16 + (lane >> 2)) * 8192 + (lane & 3) * 8;

    for (int k0 = 0; k0 < Keff; k0 += 64) {
        #pragma unroll
        for (int p = 0; p < 2; p++) {
            #pragma unroll
            for (int h = 0; h < 2; h++)
                gl_lds16(gA + (long)h * 16 * 2048 + k0 + p * 32,
                         &As[p * 4096 + (w * 32 + h * 16) * 32]);
            gl_lds16(gB + k0 + p * 32, &Bs[p * 2048 + (w * 16) * 32]);
        }
        __syncthreads();
        #pragma unroll
        for (int p = 0; p < 2; p++) {
            short8 af[2], bfr[4];
            #pragma unroll
            for (int mi = 0; mi < 2; mi++)
                af[mi] = *(const short8*)&As[p * 4096 + (w * 32 + mi * 16 + lrow) * 32 + quad * 8];
            #pragma unroll
            for (int ni = 0; ni < 4; ni++)
                bfr[ni] = *(const short8*)&Bs[p * 2048 + (ni * 16 + lrow) * 32 + quad * 8];
            #pragma unroll
            for (int mi = 0; mi < 2; mi++)
                #pragma unroll
                for (int ni = 0; ni < 4; ni++)
                    acc[mi][ni] = __builtin_amdgcn_mfma_f32_16x16x32_bf16(
                        af[mi], bfr[ni], acc[mi][ni], 0, 0, 0);
        }
        __syncthreads();
    }

    float* ob = out + (long)bz * 2048 * 1024;
    #pragma unroll
    for (int mi = 0; mi < 2; mi++) {
        const int m = m0 + w * 32 + mi * 16 + quad * 4;
        #pragma unroll
        for (int ni = 0; ni < 4; ni++) {
            const int n = n0 + ni * 16 + lrow;
            const float bvl = bvo[n];
            #pragma unroll
            for (int rg = 0; rg < 4; rg++)
                ob[(long)(m + rg) * 1024 + n] = acc[mi][ni][rg] + bvl;
        }
    }
}

// Fused QKV projection, r-FUSED: A-tile staged once per K-step for 3 B-panels.
__global__ __launch_bounds__(256, 2) void qkv_proj(
    const unsigned short* __restrict__ A,
    const unsigned short* __restrict__ Wqt, const unsigned short* __restrict__ Wkt,
    const unsigned short* __restrict__ Wvot,
    const float* __restrict__ bq, const float* __restrict__ bk,
    unsigned short* __restrict__ Q, unsigned short* __restrict__ Km,
    unsigned short* __restrict__ Vot)
{
    __shared__ __attribute__((aligned(16))) unsigned short smem[32768];  // 64 KiB
    unsigned short* As  = smem;
    unsigned short* Bs0 = smem + 8192;
    unsigned short* Bs1 = smem + 16384;
    unsigned short* Bs2 = smem + 24576;
    unsigned short* pool = smem;  // epilogue alias (32 KiB)

    const int bid = blockIdx.x;
    const int bnn = bid & 7, bm = bid >> 3;   // bnn-fastest: 8 consecutive blocks share A
    const int m0 = bm * 128, n0 = bnn * 128;

    const int t = threadIdx.x, lane = t & 63, w = t >> 6;
    const int wr = w >> 1, wc = w & 1;
    const int lrow = lane & 15, quad = lane >> 4;

    f32x4 accQ[4][4], accK[4][4], accV[4][4];
    #pragma unroll
    for (int i = 0; i < 4; i++)
        #pragma unroll
        for (int j = 0; j < 4; j++) {
            accQ[i][j] = (f32x4){0.f, 0.f, 0.f, 0.f};
            accK[i][j] = (f32x4){0.f, 0.f, 0.f, 0.f};
            accV[i][j] = (f32x4){0.f, 0.f, 0.f, 0.f};
        }

    const long rowA = (long)(m0 + w * 32 + (lane >> 2)) * 1024 + (lane & 3) * 8;
    const long rowB = (long)(n0 + w * 32 + (lane >> 2)) * 1024 + (lane & 3) * 8;
    const unsigned short* gA  = A    + rowA;
    const unsigned short* gB0 = Wqt  + rowB;
    const unsigned short* gB1 = Wkt  + rowB;
    const unsigned short* gB2 = Wvot + rowB;

    for (int k0 = 0; k0 < 1024; k0 += 64) {
        #pragma unroll
        for (int p = 0; p < 2; p++)
            #pragma unroll
            for (int h = 0; h < 2; h++) {
                const int ldst = p * 4096 + (w * 32 + h * 16) * 32;
                const long gofs = (long)h * 16 * 1024 + k0 + p * 32;
                gl_lds16(gA  + gofs, &As[ldst]);
                gl_lds16(gB0 + gofs, &Bs0[ldst]);
                gl_lds16(gB1 + gofs, &Bs1[ldst]);
                gl_lds16(gB2 + gofs, &Bs2[ldst]);
            }
        __syncthreads();
        #pragma unroll
        for (int p = 0; p < 2; p++) {
            short8 af[4], bfr[4];
            #pragma unroll
            for (int mi = 0; mi < 4; mi++)
                af[mi] = *(const short8*)&As[p * 4096 + (wr * 64 + mi * 16 + lrow) * 32 + quad * 8];
            #pragma unroll
            for (int ni = 0; ni < 4; ni++)
                bfr[ni] = *(const short8*)&Bs0[p * 4096 + (wc * 64 + ni * 16 + lrow) * 32 + quad * 8];
            #pragma unroll
            for (int mi = 0; mi < 4; mi++)
                #pragma unroll
                for (int ni = 0; ni < 4; ni++)
                    accQ[mi][ni] = __builtin_amdgcn_mfma_f32_16x16x32_bf16(
                        af[mi], bfr[ni], accQ[mi][ni], 0, 0, 0);
            #pragma unroll
            for (int ni = 0; ni < 4; ni++)
                bfr[ni] = *(const short8*)&Bs1[p * 4096 + (wc * 64 + ni * 16 + lrow) * 32 + quad * 8];
            #pragma unroll
            for (int mi = 0; mi < 4; mi++)
                #pragma unroll
                for (int ni = 0; ni < 4; ni++)
                    accK[mi][ni] = __builtin_amdgcn_mfma_f32_16x16x32_bf16(
                        af[mi], bfr[ni], accK[mi][ni], 0, 0, 0);
            #pragma unroll
            for (int ni = 0; ni < 4; ni++)
                bfr[ni] = *(const short8*)&Bs2[p * 4096 + (wc * 64 + ni * 16 + lrow) * 32 + quad * 8];
            #pragma unroll
            for (int mi = 0; mi < 4; mi++)
                #pragma unroll
                for (int ni = 0; ni < 4; ni++)
                    accV[mi][ni] = __builtin_amdgcn_mfma_f32_16x16x32_bf16(
                        af[mi], bfr[ni], accV[mi][ni], 0, 0, 0);
        }
        __syncthreads();
    }

    // --- Q epilogue (coalesced via pool) ---
    #pragma unroll
    for (int mi = 0; mi < 4; mi++)
        #pragma unroll
        for (int ni = 0; ni < 4; ni++) {
            const int n_l = wc * 64 + ni * 16 + lrow;
            const float bvl = bq[n0 + n_l];
            #pragma unroll
            for (int rg = 0; rg < 4; rg++) {
                const int m_l = wr * 64 + mi * 16 + quad * 4 + rg;
                pool[m_l * 128 + n_l] = f2b(accQ[mi][ni][rg] + bvl);
            }
        }
    __syncthreads();
    #pragma unroll
    for (int it = 0; it < 8; it++) {
        const int idx = it * 256 + t;
        const int m_l = idx >> 4, c = idx & 15;
        short8 v = *(const short8*)&pool[m_l * 128 + c * 8];
        *(short8*)&Q[(long)(m0 + m_l) * 1024 + n0 + c * 8] = v;
    }
    __syncthreads();

    // --- K epilogue ---
    #pragma unroll
    for (int mi = 0; mi < 4; mi++)
        #pragma unroll
        for (int ni = 0; ni < 4; ni++) {
            const int n_l = wc * 64 + ni * 16 + lrow;
            const float bvl = bk[n0 + n_l];
            #pragma unroll
            for (int rg = 0; rg < 4; rg++) {
                const int m_l = wr * 64 + mi * 16 + quad * 4 + rg;
                pool[m_l * 128 + n_l] = f2b(accK[mi][ni][rg] + bvl);
            }
        }
    __syncthreads();
    #pragma unroll
    for (int it = 0; it < 8; it++) {
        const int idx = it * 256 + t;
        const int m_l = idx >> 4, c = idx & 15;
        short8 v = *(const short8*)&pool[m_l * 128 + c * 8];
        *(short8*)&Km[(long)(m0 + m_l) * 1024 + n0 + c * 8] = v;
    }
    __syncthreads();

    // --- Vot epilogue (transposed, XOR-swizzled pool) ---
    #pragma unroll
    for (int mi = 0; mi < 4; mi++)
        #pragma unroll
        for (int ni = 0; ni < 4; ni++) {
            const int n_l = wc * 64 + ni * 16 + lrow;
            const int mb = wr * 64 + mi * 16 + quad * 4;
            union { unsigned short u[4]; unsigned long long ll; } pk;
            #pragma unroll
            for (int rg = 0; rg < 4; rg++) pk.u[rg] = f2b(accV[mi][ni][rg]);
            *(unsigned long long*)&pool[n_l * 128 + (mb ^ ((n_l & 15) << 3))] = pk.ll;
        }
    __syncthreads();
    #pragma unroll
    for (int it = 0; it < 8; it++) {
        const int idx = it * 256 + t;
        const int n_l = idx >> 4, c = idx & 15;
        short8 v = *(const short8*)&pool[n_l * 128 + ((c * 8) ^ ((n_l & 15) << 3))];
        *(short8*)&Vot[(long)(n0 + n_l) * 8192 + m0 + c * 8] = v;
    }
}

// Single-pass causal row softmax, 128-granular padding (PV uses 128-tile K cap).
__global__ __launch_bounds__(256) void softmax_causal(unsigned short* __restrict__ S)
{
    const int i = blockIdx.x;
    const int t = threadIdx.x;
    const int padded = ((i >> 7) + 1) << 7;
    const int j0 = t * 8;
    const bool active = j0 < padded;

    __shared__ float red[4];

    for (int b = 0; b < 4; b++) {
        unsigned short* base = S + ((long)b * 2048 + i) * 2048;

        float v[8];
        if (active) {
            short8 s8 = *(const short8*)(base + j0);
            #pragma unroll
            for (int jj = 0; jj < 8; jj++)
                v[jj] = (j0 + jj <= i) ? b2f((unsigned short)s8[jj]) : -3.0e38f;
        } else {
            #pragma unroll
            for (int jj = 0; jj < 8; jj++) v[jj] = -3.0e38f;
        }

        float lmax = v[0];
        #pragma unroll
        for (int jj = 1; jj < 8; jj++) lmax = fmaxf(lmax, v[jj]);
        #pragma unroll
        for (int off = 32; off > 0; off >>= 1) lmax = fmaxf(lmax, __shfl_xor(lmax, off, 64));
        if ((t & 63) == 0) red[t >> 6] = lmax;
        __syncthreads();
        const float gmax = fmaxf(fmaxf(red[0], red[1]), fmaxf(red[2], red[3]));
        __syncthreads();

        float lsum = 0.f;
        #pragma unroll
        for (int jj = 0; jj < 8; jj++) {
            v[jj] = (v[jj] > -1.0e37f) ? __expf(v[jj] - gmax) : 0.f;
            lsum += v[jj];
        }
        #pragma unroll
        for (int off = 32; off > 0; off >>= 1) lsum += __shfl_xor(lsum, off, 64);
        if ((t & 63) == 0) red[t >> 6] = lsum;
        __syncthreads();
        const float inv = 1.0f / (red[0] + red[1] + red[2] + red[3]);

        if (active) {
            short8 p8;
            #pragma unroll
            for (int jj = 0; jj < 8; jj++) p8[jj] = (short)f2b(v[jj] * inv);
            *(short8*)(base + j0) = p8;
        }
        __syncthreads();  // red[] reused next batch
    }
}

extern "C" void kernel_launch(void* const* d_in, const int* in_sizes, int n_in,
                              void* d_out, int out_size, void* d_ws, size_t ws_size,
                              hipStream_t stream)
{
    const float* x  = (const float*)d_in[0];
    const float* Wq = (const float*)d_in[2];
    const float* bq = (const float*)d_in[3];
    const float* Wk = (const float*)d_in[4];
    const float* bk = (const float*)d_in[5];
    const float* Wv = (const float*)d_in[6];
    const float* bv = (const float*)d_in[7];
    const float* Wo = (const float*)d_in[8];
    const float* bo = (const float*)d_in[9];

    unsigned short* ws = (unsigned short*)d_ws;
    const long XSZ = 8192L * 1024;
    const long WSZ = 1024L * 1024;
    unsigned short* xb   = ws;                // [8192,1024] bf16
    unsigned short* Wqt  = ws + XSZ;          // Wq^T bf16
    unsigned short* Wkt  = Wqt + WSZ;         // Wk^T bf16
    unsigned short* Wot  = Wkt + WSZ;         // Wo^T bf16
    unsigned short* Wvb  = Wot + WSZ;         // Wv bf16 (plain)
    unsigned short* Wvot = Wvb + WSZ;         // (Wv@Wo)^T bf16
    unsigned short* Q    = Wvot + WSZ;        // [8192,1024]
    unsigned short* Km   = Q + XSZ;           // [8192,1024]
    unsigned short* Vot  = Km + XSZ;          // [1024,8192] = (x@Wvo)^T
    unsigned short* S    = Vot + XSZ;         // [4][2048,2048] (S -> P in place)
    float*          bvo  = (float*)(S + 4L * 2048 * 2048);   // [1024] fp32

    const dim3 blk(256);

    // merged prep: weights + x convert + bvo, one dispatch
    prep<<<dim3(32, 32, 7), blk, 0, stream>>>(
        x, Wq, Wk, Wo, Wv, bv, bo, xb, Wqt, Wkt, Wot, Wvb, bvo);

    // Wvo^T = Wo^T @ Wv^T  (BK=256 single-buffered: 4 iters, 1 block/CU)
    gemm_wvo<<<dim3(8, 8), blk, 0, stream>>>(Wot, Wvb, Wvot);

    // fused QKV projection (r-fused: A staged once for 3 B-panels)
    qkv_proj<<<dim3(512), blk, 0, stream>>>(
        xb, Wqt, Wkt, Wvot, bq, bk, Q, Km, Vot);

    // S = Q K^T / sqrt(D), triangular pair grid (2 bn tiles per block)
    gemm_qk2<<<dim3(72, 4), blk, 0, stream>>>(Q, Km, S);

    softmax_causal<<<dim3(2048), blk, 0, stream>>>(S);

    // out = P @ Vo + bvo, 128x64 tiles, XCD-chunked, 5 blocks/CU capacity
    gemm_pv1<<<dim3(1024), blk, 0, stream>>>(S, Vot, bvo, (float*)d_out);
}

// Round 10
// 302.686 us; speedup vs baseline: 1.1355x; 1.0007x over previous
//
#include <hip/hip_runtime.h>
#include <hip/hip_bf16.h>

typedef __attribute__((ext_vector_type(8))) short short8;
typedef __attribute__((ext_vector_type(4))) float f32x4;

__device__ inline float b2f(unsigned short u) {
    union { unsigned int i; float f; } c; c.i = ((unsigned int)u) << 16; return c.f;
}
__device__ inline unsigned short f2b(float f) {
    __hip_bfloat16 h = __float2bfloat16(f);
    return *reinterpret_cast<unsigned short*>(&h);
}

// async global->LDS, 16 B per lane; LDS dest = wave-uniform base + lane*16
__device__ inline void gl_lds16(const unsigned short* g, unsigned short* ldsbase) {
    __builtin_amdgcn_global_load_lds(
        (const __attribute__((address_space(1))) unsigned int*)(g),
        (__attribute__((address_space(3))) unsigned int*)(ldsbase),
        16, 0, 0);
}

// ---- merged prep: weights transpose/convert + x convert + bvo, ONE dispatch ----
__global__ __launch_bounds__(256) void prep(
    const float* __restrict__ x,
    const float* __restrict__ Wq, const float* __restrict__ Wk,
    const float* __restrict__ Wo, const float* __restrict__ Wv,
    const float* __restrict__ bv, const float* __restrict__ bo,
    unsigned short* __restrict__ xb,
    unsigned short* __restrict__ Wqt, unsigned short* __restrict__ Wkt,
    unsigned short* __restrict__ Wot, unsigned short* __restrict__ Wvb,
    float* __restrict__ bvo)
{
    const int z = blockIdx.z;
    const int t = threadIdx.x;
    __shared__ float tile[32][33];

    if (z < 3) {
        const float* src = z == 0 ? Wq : z == 1 ? Wk : Wo;
        unsigned short* dst = z == 0 ? Wqt : z == 1 ? Wkt : Wot;
        const int c0 = blockIdx.x * 32, r0 = blockIdx.y * 32;
        const int tx = t & 31, ty = t >> 5;
        #pragma unroll
        for (int i = ty; i < 32; i += 8)
            tile[i][tx] = src[(long)(r0 + i) * 1024 + c0 + tx];
        __syncthreads();
        #pragma unroll
        for (int i = ty; i < 32; i += 8)
            dst[(long)(c0 + i) * 1024 + r0 + tx] = f2b(tile[tx][i]);
        return;
    }
    if (z == 3) {
        const int i = (blockIdx.y * 32 + blockIdx.x) * 256 + t;
        float4 v = ((const float4*)Wv)[i];
        union { unsigned short u[4]; unsigned long long ll; } p;
        p.u[0] = f2b(v.x); p.u[1] = f2b(v.y); p.u[2] = f2b(v.z); p.u[3] = f2b(v.w);
        ((unsigned long long*)Wvb)[i] = p.ll;
        return;
    }
    if (z < 6) {
        const int bl = (z - 4) * 1024 + blockIdx.y * 32 + blockIdx.x;
        #pragma unroll
        for (int k = 0; k < 4; k++) {
            const int i = bl * 1024 + k * 256 + t;
            float4 v = ((const float4*)x)[i];
            union { unsigned short u[4]; unsigned long long ll; } p;
            p.u[0] = f2b(v.x); p.u[1] = f2b(v.y); p.u[2] = f2b(v.z); p.u[3] = f2b(v.w);
            ((unsigned long long*)xb)[i] = p.ll;
        }
        return;
    }
    // z == 6: bvo. Only y==0 blocks work; block x handles n in [x*32, x*32+32).
    if (blockIdx.y != 0) return;
    const int tx = t & 31, ty = t >> 5;
    const int n = blockIdx.x * 32 + tx;
    float acc = 0.f;
    #pragma unroll 4
    for (int j = 0; j < 128; j++) {
        const int k = ty * 128 + j;
        acc += Wo[(long)k * 1024 + n] * bv[k];
    }
    float* red = &tile[0][0];  // reuse: 8x32 floats
    red[ty * 32 + tx] = acc;
    __syncthreads();
    if (ty == 0) {
        float s = 0.f;
        #pragma unroll
        for (int j = 0; j < 8; j++) s += red[j * 32 + tx];
        bvo[n] = s + bo[n];
    }
}

// Wvo^T = Wot @ Wvb^T, BK=256 single-buffered (4 K-iters), 1 block/CU.
// Both-sides XOR swizzle (source + read), proven r9.
__global__ __launch_bounds__(256, 1) void gemm_wvo(
    const unsigned short* __restrict__ Wot, const unsigned short* __restrict__ Wvb,
    unsigned short* __restrict__ Wvot)
{
    __shared__ __attribute__((aligned(16))) unsigned short As[128 * 256];  // 64 KB
    __shared__ __attribute__((aligned(16))) unsigned short Bs[128 * 256];  // 64 KB
    const int m0 = blockIdx.x * 128, n0 = blockIdx.y * 128;
    const int t = threadIdx.x, lane = t & 63, w = t >> 6;
    const int wr = w >> 1, wc = w & 1;
    const int lrow = lane & 15, quad = lane >> 4;

    f32x4 acc[4][4];
    #pragma unroll
    for (int i = 0; i < 4; i++)
        #pragma unroll
        for (int j = 0; j < 4; j++)
            acc[i][j] = (f32x4){0.f, 0.f, 0.f, 0.f};

    for (int k0 = 0; k0 < 1024; k0 += 256) {
        #pragma unroll
        for (int c = 0; c < 16; c++) {
            const int id = c * 256 + t;
            const int row = id >> 5;
            const int src = (id & 31) ^ (row & 7);
            gl_lds16(Wot + (long)(m0 + row) * 1024 + k0 + src * 8,
                     &As[(c * 256 + w * 64) * 8]);
            gl_lds16(Wvb + (long)(n0 + row) * 1024 + k0 + src * 8,
                     &Bs[(c * 256 + w * 64) * 8]);
        }
        __syncthreads();
        #pragma unroll
        for (int kp = 0; kp < 8; kp++) {
            short8 af[4], bfr[4];
            #pragma unroll
            for (int mi = 0; mi < 4; mi++) {
                const int r = wr * 64 + mi * 16 + lrow;
                af[mi] = *(const short8*)&As[r * 256 + (((kp * 4 + quad) ^ (r & 7)) << 3)];
            }
            #pragma unroll
            for (int ni = 0; ni < 4; ni++) {
                const int r = wc * 64 + ni * 16 + lrow;
                bfr[ni] = *(const short8*)&Bs[r * 256 + (((kp * 4 + quad) ^ (r & 7)) << 3)];
            }
            #pragma unroll
            for (int mi = 0; mi < 4; mi++)
                #pragma unroll
                for (int ni = 0; ni < 4; ni++)
                    acc[mi][ni] = __builtin_amdgcn_mfma_f32_16x16x32_bf16(
                        af[mi], bfr[ni], acc[mi][ni], 0, 0, 0);
        }
        __syncthreads();
    }

    #pragma unroll
    for (int mi = 0; mi < 4; mi++) {
        const int m = m0 + wr * 64 + mi * 16 + quad * 4;
        #pragma unroll
        for (int ni = 0; ni < 4; ni++) {
            const int n = n0 + wc * 64 + ni * 16 + lrow;
            #pragma unroll
            for (int rg = 0; rg < 4; rg++)
                Wvot[(long)(m + rg) * 1024 + n] = f2b(acc[mi][ni][rg]);
        }
    }
}

// ---- shared 2-B-panel machinery (QK2), bank-swizzled ----
// Staging slot = (lane&3)^((lane>>2)&3) on the GLOBAL source (LDS dest linear);
// read slot = quad^(row&3). 8-way conflict -> 2-way (free).
#define TILE2_DECLS \
    const int t = threadIdx.x, lane = t & 63, w = t >> 6; \
    const int wr = w >> 1, wc = w & 1; \
    const int lrow = lane & 15, quad = lane >> 4; \
    f32x4 acc0[4][4], acc1[4][4]; \
    _Pragma("unroll") for (int i = 0; i < 4; i++) \
        _Pragma("unroll") for (int j = 0; j < 4; j++) { \
            acc0[i][j] = (f32x4){0.f, 0.f, 0.f, 0.f}; \
            acc1[i][j] = (f32x4){0.f, 0.f, 0.f, 0.f}; \
        }

#define TILE2_KLOOP(gA, lda, gB0, gB1, ldb, Keff) \
    for (int k0 = 0; k0 < (Keff); k0 += 64) { \
        _Pragma("unroll") for (int p = 0; p < 2; p++) \
            _Pragma("unroll") for (int h = 0; h < 2; h++) { \
                const int ldst = p * 4096 + (w * 32 + h * 16) * 32; \
                const long gofs = (long)h * 16 * (lda) + k0 + p * 32; \
                const long gofsB = (long)h * 16 * (ldb) + k0 + p * 32; \
                gl_lds16((gA)  + gofs,  &As[ldst]); \
                gl_lds16((gB0) + gofsB, &Bs0[ldst]); \
                gl_lds16((gB1) + gofsB, &Bs1[ldst]); \
            } \
        __syncthreads(); \
        _Pragma("unroll") for (int p = 0; p < 2; p++) { \
            short8 af[4], bfr[4]; \
            _Pragma("unroll") for (int mi = 0; mi < 4; mi++) \
                af[mi] = *(const short8*)&As[p * 4096 + (wr * 64 + mi * 16 + lrow) * 32 \
                                             + ((quad ^ (lrow & 3)) << 3)]; \
            _Pragma("unroll") for (int ni = 0; ni < 4; ni++) \
                bfr[ni] = *(const short8*)&Bs0[p * 4096 + (wc * 64 + ni * 16 + lrow) * 32 \
                                               + ((quad ^ (lrow & 3)) << 3)]; \
            _Pragma("unroll") for (int mi = 0; mi < 4; mi++) \
                _Pragma("unroll") for (int ni = 0; ni < 4; ni++) \
                    acc0[mi][ni] = __builtin_amdgcn_mfma_f32_16x16x32_bf16( \
                        af[mi], bfr[ni], acc0[mi][ni], 0, 0, 0); \
            _Pragma("unroll") for (int ni = 0; ni < 4; ni++) \
                bfr[ni] = *(const short8*)&Bs1[p * 4096 + (wc * 64 + ni * 16 + lrow) * 32 \
                                               + ((quad ^ (lrow & 3)) << 3)]; \
            _Pragma("unroll") for (int mi = 0; mi < 4; mi++) \
                _Pragma("unroll") for (int ni = 0; ni < 4; ni++) \
                    acc1[mi][ni] = __builtin_amdgcn_mfma_f32_16x16x32_bf16( \
                        af[mi], bfr[ni], acc1[mi][ni], 0, 0, 0); \
        } \
        __syncthreads(); \
    }

// QK^T with triangular PAIR grid; 3 blocks/CU (accs in AGPR, vector VGPR < 170).
__global__ __launch_bounds__(256, 3) void gemm_qk2(
    const unsigned short* __restrict__ Q, const unsigned short* __restrict__ Km,
    unsigned short* __restrict__ S)
{
    __shared__ __attribute__((aligned(16))) unsigned short As[8192];
    __shared__ __attribute__((aligned(16))) unsigned short Bs0[8192];
    __shared__ __attribute__((aligned(16))) unsigned short Bs1[8192];

    const int q = 71 - blockIdx.x;  // heavy-first
    int tq = (int)sqrtf((float)q);
    while (tq * tq + tq > q) tq--;
    while ((tq + 1) * (tq + 1) + (tq + 1) <= q) tq++;
    int bm, bp;
    if (q >= (tq + 1) * (tq + 1)) { bm = 2 * tq + 1; bp = q - (tq + 1) * (tq + 1); }
    else                          { bm = 2 * tq;     bp = q - (tq * tq + tq); }
    const int bz = blockIdx.y;
    const unsigned short* A  = Q  + (long)bz * 2048 * 1024;
    const unsigned short* Bt = Km + (long)bz * 2048 * 1024;
    const int m0 = bm * 128, n0 = bp * 256;

    TILE2_DECLS

    const int csw = ((lane & 3) ^ ((lane >> 2) & 3)) * 8;  // swizzled source slot
    const unsigned short* gA  = A  + (long)(m0 + w * 32 + (lane >> 2)) * 1024 + csw;
    const unsigned short* gB0 = Bt + (long)(n0 + w * 32 + (lane >> 2)) * 1024 + csw;
    const unsigned short* gB1 = gB0 + 128L * 1024;
    TILE2_KLOOP(gA, 1024, gB0, gB1, 1024, 1024)

    unsigned short* Sb = S + (long)bz * 2048 * 2048;
    #pragma unroll
    for (int mi = 0; mi < 4; mi++) {
        const int m = m0 + wr * 64 + mi * 16 + quad * 4;
        #pragma unroll
        for (int ni = 0; ni < 4; ni++) {
            const int nl = wc * 64 + ni * 16 + lrow;
            #pragma unroll
            for (int rg = 0; rg < 4; rg++) {
                Sb[(long)(m + rg) * 2048 + n0 + nl]       = f2b(acc0[mi][ni][rg] * 0.03125f);
                Sb[(long)(m + rg) * 2048 + n0 + 128 + nl] = f2b(acc1[mi][ni][rg] * 0.03125f);
            }
        }
    }
}

// PV: 128x64 tiles, 1024 blocks, 5 blocks/CU, XCD-chunked; bank-swizzled.
__global__ __launch_bounds__(256, 5) void gemm_pv1(
    const unsigned short* __restrict__ S, const unsigned short* __restrict__ Vot,
    const float* __restrict__ bvo, float* __restrict__ out)
{
    __shared__ __attribute__((aligned(16))) unsigned short As[8192];  // 128x64 bf16
    __shared__ __attribute__((aligned(16))) unsigned short Bs[4096];  //  64x64 bf16

    const int bid = blockIdx.x;
    const int xcd = bid & 7, s = bid >> 3;
    const int bn = s & 15, j = s >> 4;          // bn fastest within the XCD chunk
    const int rank = j * 8 + xcd;               // 0..63, heavy-first in dispatch order
    const int bz = rank & 3;
    const int bm = 15 - (rank >> 2);
    const unsigned short* A  = S   + (long)bz * 2048 * 2048;
    const unsigned short* Bt = Vot + (long)bz * 2048;
    const int m0 = bm * 128, n0 = bn * 64;
    const int Keff = (bm + 1) * 128;

    const int t = threadIdx.x, lane = t & 63, w = t >> 6;
    const int lrow = lane & 15, quad = lane >> 4;

    f32x4 acc[2][4];
    #pragma unroll
    for (int i = 0; i < 2; i++)
        #pragma unroll
        for (int jj = 0; jj < 4; jj++)
            acc[i][jj] = (f32x4){0.f, 0.f, 0.f, 0.f};

    const int csw = ((lane & 3) ^ ((lane >> 2) & 3)) * 8;
    const unsigned short* gA = A  + (long)(m0 + w * 32 + (lane >> 2)) * 2048 + csw;
    const unsigned short* gB = Bt + (long)(n0 + w * 16 + (lane >> 2)) * 8192 + csw;

    for (int k0 = 0; k0 < Keff; k0 += 64) {
        #pragma unroll
        for (int p = 0; p < 2; p++) {
            #pragma unroll
            for (int h = 0; h < 2; h++)
                gl_lds16(gA + (long)h * 16 * 2048 + k0 + p * 32,
                         &As[p * 4096 + (w * 32 + h * 16) * 32]);
            gl_lds16(gB + k0 + p * 32, &Bs[p * 2048 + (w * 16) * 32]);
        }
        __syncthreads();
        #pragma unroll
        for (int p = 0; p < 2; p++) {
            short8 af[2], bfr[4];
            #pragma unroll
            for (int mi = 0; mi < 2; mi++)
                af[mi] = *(const short8*)&As[p * 4096 + (w * 32 + mi * 16 + lrow) * 32
                                             + ((quad ^ (lrow & 3)) << 3)];
            #pragma unroll
            for (int ni = 0; ni < 4; ni++)
                bfr[ni] = *(const short8*)&Bs[p * 2048 + (ni * 16 + lrow) * 32
                                              + ((quad ^ (lrow & 3)) << 3)];
            #pragma unroll
            for (int mi = 0; mi < 2; mi++)
                #pragma unroll
                for (int ni = 0; ni < 4; ni++)
                    acc[mi][ni] = __builtin_amdgcn_mfma_f32_16x16x32_bf16(
                        af[mi], bfr[ni], acc[mi][ni], 0, 0, 0);
        }
        __syncthreads();
    }

    float* ob = out + (long)bz * 2048 * 1024;
    #pragma unroll
    for (int mi = 0; mi < 2; mi++) {
        const int m = m0 + w * 32 + mi * 16 + quad * 4;
        #pragma unroll
        for (int ni = 0; ni < 4; ni++) {
            const int n = n0 + ni * 16 + lrow;
            const float bvl = bvo[n];
            #pragma unroll
            for (int rg = 0; rg < 4; rg++)
                ob[(long)(m + rg) * 1024 + n] = acc[mi][ni][rg] + bvl;
        }
    }
}

// Fused QKV projection, r-FUSED; bank-swizzled staging/reads.
__global__ __launch_bounds__(256, 2) void qkv_proj(
    const unsigned short* __restrict__ A,
    const unsigned short* __restrict__ Wqt, const unsigned short* __restrict__ Wkt,
    const unsigned short* __restrict__ Wvot,
    const float* __restrict__ bq, const float* __restrict__ bk,
    unsigned short* __restrict__ Q, unsigned short* __restrict__ Km,
    unsigned short* __restrict__ Vot)
{
    __shared__ __attribute__((aligned(16))) unsigned short smem[32768];  // 64 KiB
    unsigned short* As  = smem;
    unsigned short* Bs0 = smem + 8192;
    unsigned short* Bs1 = smem + 16384;
    unsigned short* Bs2 = smem + 24576;
    unsigned short* pool = smem;  // epilogue alias (32 KiB)

    const int bid = blockIdx.x;
    const int bnn = bid & 7, bm = bid >> 3;   // bnn-fastest: 8 consecutive blocks share A
    const int m0 = bm * 128, n0 = bnn * 128;

    const int t = threadIdx.x, lane = t & 63, w = t >> 6;
    const int wr = w >> 1, wc = w & 1;
    const int lrow = lane & 15, quad = lane >> 4;

    f32x4 accQ[4][4], accK[4][4], accV[4][4];
    #pragma unroll
    for (int i = 0; i < 4; i++)
        #pragma unroll
        for (int j = 0; j < 4; j++) {
            accQ[i][j] = (f32x4){0.f, 0.f, 0.f, 0.f};
            accK[i][j] = (f32x4){0.f, 0.f, 0.f, 0.f};
            accV[i][j] = (f32x4){0.f, 0.f, 0.f, 0.f};
        }

    const int csw = ((lane & 3) ^ ((lane >> 2) & 3)) * 8;  // swizzled source slot
    const long rowA = (long)(m0 + w * 32 + (lane >> 2)) * 1024 + csw;
    const long rowB = (long)(n0 + w * 32 + (lane >> 2)) * 1024 + csw;
    const unsigned short* gA  = A    + rowA;
    const unsigned short* gB0 = Wqt  + rowB;
    const unsigned short* gB1 = Wkt  + rowB;
    const unsigned short* gB2 = Wvot + rowB;

    for (int k0 = 0; k0 < 1024; k0 += 64) {
        #pragma unroll
        for (int p = 0; p < 2; p++)
            #pragma unroll
            for (int h = 0; h < 2; h++) {
                const int ldst = p * 4096 + (w * 32 + h * 16) * 32;
                const long gofs = (long)h * 16 * 1024 + k0 + p * 32;
                gl_lds16(gA  + gofs, &As[ldst]);
                gl_lds16(gB0 + gofs, &Bs0[ldst]);
                gl_lds16(gB1 + gofs, &Bs1[ldst]);
                gl_lds16(gB2 + gofs, &Bs2[ldst]);
            }
        __syncthreads();
        #pragma unroll
        for (int p = 0; p < 2; p++) {
            const int rsw = (quad ^ (lrow & 3)) << 3;  // swizzled read slot
            short8 af[4], bfr[4];
            #pragma unroll
            for (int mi = 0; mi < 4; mi++)
                af[mi] = *(const short8*)&As[p * 4096 + (wr * 64 + mi * 16 + lrow) * 32 + rsw];
            #pragma unroll
            for (int ni = 0; ni < 4; ni++)
                bfr[ni] = *(const short8*)&Bs0[p * 4096 + (wc * 64 + ni * 16 + lrow) * 32 + rsw];
            #pragma unroll
            for (int mi = 0; mi < 4; mi++)
                #pragma unroll
                for (int ni = 0; ni < 4; ni++)
                    accQ[mi][ni] = __builtin_amdgcn_mfma_f32_16x16x32_bf16(
                        af[mi], bfr[ni], accQ[mi][ni], 0, 0, 0);
            #pragma unroll
            for (int ni = 0; ni < 4; ni++)
                bfr[ni] = *(const short8*)&Bs1[p * 4096 + (wc * 64 + ni * 16 + lrow) * 32 + rsw];
            #pragma unroll
            for (int mi = 0; mi < 4; mi++)
                #pragma unroll
                for (int ni = 0; ni < 4; ni++)
                    accK[mi][ni] = __builtin_amdgcn_mfma_f32_16x16x32_bf16(
                        af[mi], bfr[ni], accK[mi][ni], 0, 0, 0);
            #pragma unroll
            for (int ni = 0; ni < 4; ni++)
                bfr[ni] = *(const short8*)&Bs2[p * 4096 + (wc * 64 + ni * 16 + lrow) * 32 + rsw];
            #pragma unroll
            for (int mi = 0; mi < 4; mi++)
                #pragma unroll
                for (int ni = 0; ni < 4; ni++)
                    accV[mi][ni] = __builtin_amdgcn_mfma_f32_16x16x32_bf16(
                        af[mi], bfr[ni], accV[mi][ni], 0, 0, 0);
        }
        __syncthreads();
    }

    // --- Q epilogue (coalesced via pool) ---
    #pragma unroll
    for (int mi = 0; mi < 4; mi++)
        #pragma unroll
        for (int ni = 0; ni < 4; ni++) {
            const int n_l = wc * 64 + ni * 16 + lrow;
            const float bvl = bq[n0 + n_l];
            #pragma unroll
            for (int rg = 0; rg < 4; rg++) {
                const int m_l = wr * 64 + mi * 16 + quad * 4 + rg;
                pool[m_l * 128 + n_l] = f2b(accQ[mi][ni][rg] + bvl);
            }
        }
    __syncthreads();
    #pragma unroll
    for (int it = 0; it < 8; it++) {
        const int idx = it * 256 + t;
        const int m_l = idx >> 4, c = idx & 15;
        short8 v = *(const short8*)&pool[m_l * 128 + c * 8];
        *(short8*)&Q[(long)(m0 + m_l) * 1024 + n0 + c * 8] = v;
    }
    __syncthreads();

    // --- K epilogue ---
    #pragma unroll
    for (int mi = 0; mi < 4; mi++)
        #pragma unroll
        for (int ni = 0; ni < 4; ni++) {
            const int n_l = wc * 64 + ni * 16 + lrow;
            const float bvl = bk[n0 + n_l];
            #pragma unroll
            for (int rg = 0; rg < 4; rg++) {
                const int m_l = wr * 64 + mi * 16 + quad * 4 + rg;
                pool[m_l * 128 + n_l] = f2b(accK[mi][ni][rg] + bvl);
            }
        }
    __syncthreads();
    #pragma unroll
    for (int it = 0; it < 8; it++) {
        const int idx = it * 256 + t;
        const int m_l = idx >> 4, c = idx & 15;
        short8 v = *(const short8*)&pool[m_l * 128 + c * 8];
        *(short8*)&Km[(long)(m0 + m_l) * 1024 + n0 + c * 8] = v;
    }
    __syncthreads();

    // --- Vot epilogue (transposed, XOR-swizzled pool) ---
    #pragma unroll
    for (int mi = 0; mi < 4; mi++)
        #pragma unroll
        for (int ni = 0; ni < 4; ni++) {
            const int n_l = wc * 64 + ni * 16 + lrow;
            const int mb = wr * 64 + mi * 16 + quad * 4;
            union { unsigned short u[4]; unsigned long long ll; } pk;
            #pragma unroll
            for (int rg = 0; rg < 4; rg++) pk.u[rg] = f2b(accV[mi][ni][rg]);
            *(unsigned long long*)&pool[n_l * 128 + (mb ^ ((n_l & 15) << 3))] = pk.ll;
        }
    __syncthreads();
    #pragma unroll
    for (int it = 0; it < 8; it++) {
        const int idx = it * 256 + t;
        const int n_l = idx >> 4, c = idx & 15;
        short8 v = *(const short8*)&pool[n_l * 128 + ((c * 8) ^ ((n_l & 15) << 3))];
        *(short8*)&Vot[(long)(n0 + n_l) * 8192 + m0 + c * 8] = v;
    }
}

// Single-pass causal row softmax, 128-granular padding (PV uses 128-tile K cap).
__global__ __launch_bounds__(256) void softmax_causal(unsigned short* __restrict__ S)
{
    const int i = blockIdx.x;
    const int t = threadIdx.x;
    const int padded = ((i >> 7) + 1) << 7;
    const int j0 = t * 8;
    const bool active = j0 < padded;

    __shared__ float red[4];

    for (int b = 0; b < 4; b++) {
        unsigned short* base = S + ((long)b * 2048 + i) * 2048;

        float v[8];
        if (active) {
            short8 s8 = *(const short8*)(base + j0);
            #pragma unroll
            for (int jj = 0; jj < 8; jj++)
                v[jj] = (j0 + jj <= i) ? b2f((unsigned short)s8[jj]) : -3.0e38f;
        } else {
            #pragma unroll
            for (int jj = 0; jj < 8; jj++) v[jj] = -3.0e38f;
        }

        float lmax = v[0];
        #pragma unroll
        for (int jj = 1; jj < 8; jj++) lmax = fmaxf(lmax, v[jj]);
        #pragma unroll
        for (int off = 32; off > 0; off >>= 1) lmax = fmaxf(lmax, __shfl_xor(lmax, off, 64));
        if ((t & 63) == 0) red[t >> 6] = lmax;
        __syncthreads();
        const float gmax = fmaxf(fmaxf(red[0], red[1]), fmaxf(red[2], red[3]));
        __syncthreads();

        float lsum = 0.f;
        #pragma unroll
        for (int jj = 0; jj < 8; jj++) {
            v[jj] = (v[jj] > -1.0e37f) ? __expf(v[jj] - gmax) : 0.f;
            lsum += v[jj];
        }
        #pragma unroll
        for (int off = 32; off > 0; off >>= 1) lsum += __shfl_xor(lsum, off, 64);
        if ((t & 63) == 0) red[t >> 6] = lsum;
        __syncthreads();
        const float inv = 1.0f / (red[0] + red[1] + red[2] + red[3]);

        if (active) {
            short8 p8;
            #pragma unroll
            for (int jj = 0; jj < 8; jj++) p8[jj] = (short)f2b(v[jj] * inv);
            *(short8*)(base + j0) = p8;
        }
        __syncthreads();  // red[] reused next batch
    }
}

extern "C" void kernel_launch(void* const* d_in, const int* in_sizes, int n_in,
                              void* d_out, int out_size, void* d_ws, size_t ws_size,
                              hipStream_t stream)
{
    const float* x  = (const float*)d_in[0];
    const float* Wq = (const float*)d_in[2];
    const float* bq = (const float*)d_in[3];
    const float* Wk = (const float*)d_in[4];
    const float* bk = (const float*)d_in[5];
    const float* Wv = (const float*)d_in[6];
    const float* bv = (const float*)d_in[7];
    const float* Wo = (const float*)d_in[8];
    const float* bo = (const float*)d_in[9];

    unsigned short* ws = (unsigned short*)d_ws;
    const long XSZ = 8192L * 1024;
    const long WSZ = 1024L * 1024;
    unsigned short* xb   = ws;                // [8192,1024] bf16
    unsigned short* Wqt  = ws + XSZ;          // Wq^T bf16
    unsigned short* Wkt  = Wqt + WSZ;         // Wk^T bf16
    unsigned short* Wot  = Wkt + WSZ;         // Wo^T bf16
    unsigned short* Wvb  = Wot + WSZ;         // Wv bf16 (plain)
    unsigned short* Wvot = Wvb + WSZ;         // (Wv@Wo)^T bf16
    unsigned short* Q    = Wvot + WSZ;        // [8192,1024]
    unsigned short* Km   = Q + XSZ;           // [8192,1024]
    unsigned short* Vot  = Km + XSZ;          // [1024,8192] = (x@Wvo)^T
    unsigned short* S    = Vot + XSZ;         // [4][2048,2048] (S -> P in place)
    float*          bvo  = (float*)(S + 4L * 2048 * 2048);   // [1024] fp32

    const dim3 blk(256);

    // merged prep: weights + x convert + bvo, one dispatch
    prep<<<dim3(32, 32, 7), blk, 0, stream>>>(
        x, Wq, Wk, Wo, Wv, bv, bo, xb, Wqt, Wkt, Wot, Wvb, bvo);

    // Wvo^T = Wo^T @ Wv^T  (BK=256 single-buffered: 4 iters, 1 block/CU)
    gemm_wvo<<<dim3(8, 8), blk, 0, stream>>>(Wot, Wvb, Wvot);

    // fused QKV projection (r-fused, bank-swizzled)
    qkv_proj<<<dim3(512), blk, 0, stream>>>(
        xb, Wqt, Wkt, Wvot, bq, bk, Q, Km, Vot);

    // S = Q K^T / sqrt(D), triangular pair grid, 3 blocks/CU, bank-swizzled
    gemm_qk2<<<dim3(72, 4), blk, 0, stream>>>(Q, Km, S);

    softmax_causal<<<dim3(2048), blk, 0, stream>>>(S);

    // out = P @ Vo + bvo, 128x64 tiles, XCD-chunked, 5 blocks/CU, bank-swizzled
    gemm_pv1<<<dim3(1024), blk, 0, stream>>>(S, Vot, bvo, (float*)d_out);
}